// Round 2
// baseline (1563.368 us; speedup 1.0000x reference)
//
#include <hip/hip_runtime.h>
#include <hip/hip_bf16.h>

#define NEG_SLOPE 0.2f

// ---------------- CSR build ----------------
__global__ void zero_int_kernel(int* __restrict__ p, int n) {
  int i = blockIdx.x * blockDim.x + threadIdx.x;
  if (i < n) p[i] = 0;
}

__global__ void hist_kernel(const int* __restrict__ dst, int* __restrict__ deg, int E) {
  int e = blockIdx.x * blockDim.x + threadIdx.x;
  if (e < E) atomicAdd(&deg[dst[e]], 1);
}

// block scans 1024 elements (256 thr x 4); writes per-element exclusive scan + block sum
__global__ void scan1_kernel(const int* __restrict__ deg, int* __restrict__ part,
                             int* __restrict__ bsums, int n) {
  __shared__ int sdata[256];
  int t = threadIdx.x;
  int base = blockIdx.x * 1024;
  int v[4]; int s = 0;
#pragma unroll
  for (int j = 0; j < 4; ++j) {
    int idx = base + t * 4 + j;
    v[j] = (idx < n) ? deg[idx] : 0;
    s += v[j];
  }
  sdata[t] = s;
  __syncthreads();
  for (int off = 1; off < 256; off <<= 1) {
    int x = 0;
    if (t >= off) x = sdata[t - off];
    __syncthreads();
    if (t >= off) sdata[t] += x;
    __syncthreads();
  }
  if (t == 255) bsums[blockIdx.x] = sdata[255];
  int run = (t > 0) ? sdata[t - 1] : 0;
#pragma unroll
  for (int j = 0; j < 4; ++j) {
    int idx = base + t * 4 + j;
    if (idx < n) part[idx] = run;
    run += v[j];
  }
}

// single block: exclusive scan of nb (<=256) block sums in place
__global__ void scan2_kernel(int* __restrict__ bsums, int nb) {
  __shared__ int sdata[256];
  int t = threadIdx.x;
  sdata[t] = (t < nb) ? bsums[t] : 0;
  __syncthreads();
  for (int off = 1; off < 256; off <<= 1) {
    int x = 0;
    if (t >= off) x = sdata[t - off];
    __syncthreads();
    if (t >= off) sdata[t] += x;
    __syncthreads();
  }
  if (t < nb) bsums[t] = (t > 0) ? sdata[t - 1] : 0;
}

__global__ void scan3_kernel(const int* __restrict__ part, const int* __restrict__ bsums,
                             int* __restrict__ rowptr, int* __restrict__ cursor,
                             int n, int Etot) {
  int i = blockIdx.x * blockDim.x + threadIdx.x;
  if (i < n) {
    int v = part[i] + bsums[i >> 10];
    rowptr[i] = v;
    cursor[i] = v;
  }
  if (i == 0) rowptr[n] = Etot;
}

__global__ void scatter_kernel(const int* __restrict__ src, const int* __restrict__ dst,
                               int* __restrict__ cursor, int* __restrict__ csr_src, int E) {
  int e = blockIdx.x * blockDim.x + threadIdx.x;
  if (e < E) {
    int pos = atomicAdd(&cursor[dst[e]], 1);
    csr_src[pos] = src[e];
  }
}

// ---------------- GEMM: C[M,Nc] = A[M,K] * B[K,Nc], float32 ----------------
#define TBM 64
#define TBN 64
#define TBK 32

__global__ __launch_bounds__(256) void gemm_f32_kernel(
    const float* __restrict__ A, const float* __restrict__ B, float* __restrict__ C,
    int M, int K, int Nc) {
  __shared__ float As[TBK][TBM + 4];
  __shared__ float Bs[TBK][TBN + 4];
  int tid = threadIdx.x;
  int tx = tid & 15, ty = tid >> 4;
  int rowBase = blockIdx.y * TBM;
  int colBase = blockIdx.x * TBN;

  float acc[4][4] = {};

  int arow = tid >> 2;        // 0..63
  int ak = (tid & 3) * 8;     // 0,8,16,24
  int brow = tid >> 3;        // 0..31
  int bcol = (tid & 7) * 8;   // 0..56

  for (int k0 = 0; k0 < K; k0 += TBK) {
    // A tile: 64 rows x 32 k, two float4 per thread
    {
      int r = rowBase + arow;
      float vals[8];
      if (r < M) {
        const float* ap = A + (size_t)r * K + k0 + ak;
        float4 u0 = *(const float4*)(ap);
        float4 u1 = *(const float4*)(ap + 4);
        vals[0] = u0.x; vals[1] = u0.y; vals[2] = u0.z; vals[3] = u0.w;
        vals[4] = u1.x; vals[5] = u1.y; vals[6] = u1.z; vals[7] = u1.w;
      } else {
#pragma unroll
        for (int j = 0; j < 8; ++j) vals[j] = 0.f;
      }
#pragma unroll
      for (int j = 0; j < 8; ++j) As[ak + j][arow] = vals[j];
    }
    // B tile: 32 k x 64 cols, scalar (col guard for Nc=188)
    {
      int kr = k0 + brow;
      const float* bp = B + (size_t)kr * Nc;
#pragma unroll
      for (int j = 0; j < 8; ++j) {
        int c = colBase + bcol + j;
        Bs[brow][bcol + j] = (c < Nc) ? bp[c] : 0.f;
      }
    }
    __syncthreads();
#pragma unroll
    for (int kk = 0; kk < TBK; ++kk) {
      float4 av = *(const float4*)&As[kk][ty * 4];
      float4 bv = *(const float4*)&Bs[kk][tx * 4];
      float a[4] = {av.x, av.y, av.z, av.w};
      float b[4] = {bv.x, bv.y, bv.z, bv.w};
#pragma unroll
      for (int i = 0; i < 4; ++i)
#pragma unroll
        for (int j = 0; j < 4; ++j) acc[i][j] += a[i] * b[j];
    }
    __syncthreads();
  }
#pragma unroll
  for (int i = 0; i < 4; ++i) {
    int r = rowBase + ty * 4 + i;
    if (r < M) {
#pragma unroll
      for (int j = 0; j < 4; ++j) {
        int c = colBase + tx * 4 + j;
        if (c < Nc) C[(size_t)r * Nc + c] = acc[i][j];
      }
    }
  }
}

// ---------------- el/er: [N,H] = sum_d feat[n,h,d]*al/ar[h,d] ----------------
__global__ void elr_kernel(const float* __restrict__ feat, const float* __restrict__ al,
                           const float* __restrict__ ar, float* __restrict__ el,
                           float* __restrict__ er, int N, int Dh, int Fd) {
  int g = blockIdx.x * blockDim.x + threadIdx.x;
  if (g >= N * 4) return;
  int n = g >> 2, h = g & 3;
  const float* fp = feat + (size_t)n * Fd + h * Dh;
  float sl = 0.f, sr = 0.f;
  for (int d = 0; d < Dh; ++d) {
    float f = fp[d];
    sl += f * al[h * Dh + d];
    sr += f * ar[h * Dh + d];
  }
  el[g] = sl;
  er[g] = sr;
}

// ---------------- layer 1/2 aggregation: F=128, one wave per dst node ----------------
__global__ __launch_bounds__(256) void agg128_kernel(
    const int* __restrict__ rowptr, const int* __restrict__ csr_src,
    const float* __restrict__ feat, const float* __restrict__ el,
    const float* __restrict__ er, const float* __restrict__ bias,
    float* __restrict__ hout, int N) {
  int lane = threadIdx.x & 63;
  int v = blockIdx.x * 4 + (threadIdx.x >> 6);
  if (v >= N) return;
  float erh[4];
#pragma unroll
  for (int h = 0; h < 4; ++h) erh[h] = er[v * 4 + h];
  int r0 = rowptr[v], r1 = rowptr[v + 1];
  // pass 1: per-head max over edges (edges strided over lanes)
  float m[4] = {-1e30f, -1e30f, -1e30f, -1e30f};
  for (int i = r0 + lane; i < r1; i += 64) {
    int s = csr_src[i];
#pragma unroll
    for (int h = 0; h < 4; ++h) {
      float e = el[s * 4 + h] + erh[h];
      e = (e > 0.f) ? e : NEG_SLOPE * e;
      m[h] = fmaxf(m[h], e);
    }
  }
#pragma unroll
  for (int off = 32; off > 0; off >>= 1) {
#pragma unroll
    for (int h = 0; h < 4; ++h) m[h] = fmaxf(m[h], __shfl_xor(m[h], off));
  }
  // pass 2: all lanes walk all edges; lane owns features lane and lane+64
  int f0 = lane, f1 = lane + 64;
  int h0 = lane >> 5, h1 = 2 + (lane >> 5);
  float acc0 = 0.f, acc1 = 0.f, den0 = 0.f, den1 = 0.f;
  for (int i = r0; i < r1; ++i) {
    int s = csr_src[i];
    float e0 = el[s * 4 + h0] + erh[h0];
    e0 = (e0 > 0.f) ? e0 : NEG_SLOPE * e0;
    float x0 = __expf(e0 - m[h0]);
    float e1 = el[s * 4 + h1] + erh[h1];
    e1 = (e1 > 0.f) ? e1 : NEG_SLOPE * e1;
    float x1 = __expf(e1 - m[h1]);
    den0 += x0;
    den1 += x1;
    acc0 += x0 * feat[(size_t)s * 128 + f0];
    acc1 += x1 * feat[(size_t)s * 128 + f1];
  }
  float o0 = (den0 > 0.f) ? acc0 / den0 : 0.f;
  float o1 = (den1 > 0.f) ? acc1 / den1 : 0.f;
  o0 = fmaxf(o0 + bias[f0], 0.f);
  o1 = fmaxf(o1 + bias[f1], 0.f);
  hout[(size_t)v * 128 + f0] = o0;
  hout[(size_t)v * 128 + f1] = o1;
}

// ---------------- layer 3 aggregation + bias + head-mean + log_softmax ----------------
__global__ __launch_bounds__(256) void agg3_kernel(
    const int* __restrict__ rowptr, const int* __restrict__ csr_src,
    const float* __restrict__ feat, const float* __restrict__ el,
    const float* __restrict__ er, const float* __restrict__ bias,
    float* __restrict__ out, int N) {
  __shared__ float sv[4][188];
  int lane = threadIdx.x & 63;
  int w = threadIdx.x >> 6;
  int v = blockIdx.x * 4 + w;
  bool valid = (v < N);
  float erh[4] = {0.f, 0.f, 0.f, 0.f};
  int r0 = 0, r1 = 0;
  if (valid) {
#pragma unroll
    for (int h = 0; h < 4; ++h) erh[h] = er[v * 4 + h];
    r0 = rowptr[v];
    r1 = rowptr[v + 1];
  }
  float m[4] = {-1e30f, -1e30f, -1e30f, -1e30f};
  for (int i = r0 + lane; i < r1; i += 64) {
    int s = csr_src[i];
#pragma unroll
    for (int h = 0; h < 4; ++h) {
      float e = el[s * 4 + h] + erh[h];
      e = (e > 0.f) ? e : NEG_SLOPE * e;
      m[h] = fmaxf(m[h], e);
    }
  }
#pragma unroll
  for (int off = 32; off > 0; off >>= 1) {
#pragma unroll
    for (int h = 0; h < 4; ++h) m[h] = fmaxf(m[h], __shfl_xor(m[h], off));
  }
  // lane owns features lane, lane+64, lane+128 (f = h*47 + c)
  int f0 = lane, f1 = lane + 64, f2 = lane + 128;
  bool has2 = (f2 < 188);
  int h0 = f0 / 47, h1 = f1 / 47, h2 = has2 ? (f2 / 47) : 3;
  float acc0 = 0.f, acc1 = 0.f, acc2 = 0.f;
  float den0 = 0.f, den1 = 0.f, den2 = 0.f;
  for (int i = r0; i < r1; ++i) {
    int s = csr_src[i];
    float e0 = el[s * 4 + h0] + erh[h0];
    e0 = (e0 > 0.f) ? e0 : NEG_SLOPE * e0;
    float x0 = __expf(e0 - m[h0]);
    float e1 = el[s * 4 + h1] + erh[h1];
    e1 = (e1 > 0.f) ? e1 : NEG_SLOPE * e1;
    float x1 = __expf(e1 - m[h1]);
    float e2 = el[s * 4 + h2] + erh[h2];
    e2 = (e2 > 0.f) ? e2 : NEG_SLOPE * e2;
    float x2 = __expf(e2 - m[h2]);
    den0 += x0;
    den1 += x1;
    den2 += x2;
    acc0 += x0 * feat[(size_t)s * 188 + f0];
    acc1 += x1 * feat[(size_t)s * 188 + f1];
    if (has2) acc2 += x2 * feat[(size_t)s * 188 + f2];
  }
  float o0 = ((den0 > 0.f) ? acc0 / den0 : 0.f) + bias[f0];
  float o1 = ((den1 > 0.f) ? acc1 / den1 : 0.f) + bias[f1];
  float o2 = has2 ? (((den2 > 0.f) ? acc2 / den2 : 0.f) + bias[f2]) : 0.f;
  if (valid) {
    sv[w][f0] = o0;
    sv[w][f1] = o1;
    if (has2) sv[w][f2] = o2;
  }
  __syncthreads();
  float val = -1e30f;
  if (valid && lane < 47)
    val = 0.25f * (sv[w][lane] + sv[w][47 + lane] + sv[w][94 + lane] + sv[w][141 + lane]);
  float mx = val;
#pragma unroll
  for (int off = 32; off > 0; off >>= 1) mx = fmaxf(mx, __shfl_xor(mx, off));
  float ex = (lane < 47) ? __expf(val - mx) : 0.f;
  float sum = ex;
#pragma unroll
  for (int off = 32; off > 0; off >>= 1) sum += __shfl_xor(sum, off);
  float res = val - mx - logf(sum);
  if (valid && lane < 47) out[(size_t)v * 47 + lane] = res;
}

// ---------------- host orchestration ----------------
extern "C" void kernel_launch(void* const* d_in, const int* in_sizes, int n_in,
                              void* d_out, int out_size, void* d_ws, size_t ws_size,
                              hipStream_t stream) {
  const int N = 100000, E = 1600000, IN = 256;
  const int F = 128;   // H*D
  const int F3 = 188;  // H*C

  const float* x = (const float*)d_in[0];
  const int* src = (const int*)d_in[1];
  const int* dst = (const int*)d_in[2];
  const float* W1 = (const float*)d_in[3];
  const float* al1 = (const float*)d_in[4];
  const float* ar1 = (const float*)d_in[5];
  const float* b1 = (const float*)d_in[6];
  const float* W2 = (const float*)d_in[7];
  const float* al2 = (const float*)d_in[8];
  const float* ar2 = (const float*)d_in[9];
  const float* b2 = (const float*)d_in[10];
  const float* W3 = (const float*)d_in[11];
  const float* al3 = (const float*)d_in[12];
  const float* ar3 = (const float*)d_in[13];
  const float* b3 = (const float*)d_in[14];

  char* p = (char*)d_ws;
  auto alloc = [&](size_t bytes) -> char* {
    char* r = p;
    p += (bytes + 255) & ~(size_t)255;
    return r;
  };
  float* feat = (float*)alloc((size_t)N * F3 * sizeof(float));   // GEMM output per layer
  float* hbuf = (float*)alloc((size_t)N * F * sizeof(float));    // aggregated hidden
  float* el = (float*)alloc((size_t)N * 4 * sizeof(float));
  float* er = (float*)alloc((size_t)N * 4 * sizeof(float));
  int* deg = (int*)alloc((size_t)N * sizeof(int));
  int* part = (int*)alloc((size_t)N * sizeof(int));
  int* bsums = (int*)alloc(256 * sizeof(int));
  int* rowptr = (int*)alloc((size_t)(N + 1) * sizeof(int));
  int* cursor = (int*)alloc((size_t)N * sizeof(int));
  int* csr_src = (int*)alloc((size_t)E * sizeof(int));

  // ---- CSR build (graph is identical for all 3 layers) ----
  zero_int_kernel<<<(N + 255) / 256, 256, 0, stream>>>(deg, N);
  hist_kernel<<<(E + 255) / 256, 256, 0, stream>>>(dst, deg, E);
  int nb = (N + 1023) / 1024;  // 98
  scan1_kernel<<<nb, 256, 0, stream>>>(deg, part, bsums, N);
  scan2_kernel<<<1, 256, 0, stream>>>(bsums, nb);
  scan3_kernel<<<(N + 255) / 256, 256, 0, stream>>>(part, bsums, rowptr, cursor, N, E);
  scatter_kernel<<<(E + 255) / 256, 256, 0, stream>>>(src, dst, cursor, csr_src, E);

  int rowBlocks = (N + TBM - 1) / TBM;  // 1563

  // ---- layer 1: IN=256 -> 128 ----
  gemm_f32_kernel<<<dim3(F / TBN, rowBlocks), 256, 0, stream>>>(x, W1, feat, N, IN, F);
  elr_kernel<<<(N * 4 + 255) / 256, 256, 0, stream>>>(feat, al1, ar1, el, er, N, 32, F);
  agg128_kernel<<<(N + 3) / 4, 256, 0, stream>>>(rowptr, csr_src, feat, el, er, b1, hbuf, N);

  // ---- layer 2: 128 -> 128 ----
  gemm_f32_kernel<<<dim3(F / TBN, rowBlocks), 256, 0, stream>>>(hbuf, W2, feat, N, F, F);
  elr_kernel<<<(N * 4 + 255) / 256, 256, 0, stream>>>(feat, al2, ar2, el, er, N, 32, F);
  agg128_kernel<<<(N + 3) / 4, 256, 0, stream>>>(rowptr, csr_src, feat, el, er, b2, hbuf, N);

  // ---- layer 3: 128 -> 188, fused epilogue ----
  gemm_f32_kernel<<<dim3((F3 + TBN - 1) / TBN, rowBlocks), 256, 0, stream>>>(hbuf, W3, feat, N, F, F3);
  elr_kernel<<<(N * 4 + 255) / 256, 256, 0, stream>>>(feat, al3, ar3, el, er, N, 47, F3);
  agg3_kernel<<<(N + 3) / 4, 256, 0, stream>>>(rowptr, csr_src, feat, el, er, b3,
                                               (float*)d_out, N);
}

// Round 3
// 1364.791 us; speedup vs baseline: 1.1455x; 1.1455x over previous
//
#include <hip/hip_runtime.h>
#include <hip/hip_bf16.h>

typedef __hip_bfloat16 bf16;
#define NEG_SLOPE 0.2f

__device__ __forceinline__ float b2f(bf16 x) { return __bfloat162float(x); }

// ---------------- CSR build ----------------
__global__ void zero_int_kernel(int* __restrict__ p, int n) {
  int i = blockIdx.x * blockDim.x + threadIdx.x;
  if (i < n) p[i] = 0;
}

__global__ void hist_kernel(const int* __restrict__ dst, int* __restrict__ deg, int E) {
  int e = blockIdx.x * blockDim.x + threadIdx.x;
  if (e < E) atomicAdd(&deg[dst[e]], 1);
}

__global__ void scan1_kernel(const int* __restrict__ deg, int* __restrict__ part,
                             int* __restrict__ bsums, int n) {
  __shared__ int sdata[256];
  int t = threadIdx.x;
  int base = blockIdx.x * 1024;
  int v[4]; int s = 0;
#pragma unroll
  for (int j = 0; j < 4; ++j) {
    int idx = base + t * 4 + j;
    v[j] = (idx < n) ? deg[idx] : 0;
    s += v[j];
  }
  sdata[t] = s;
  __syncthreads();
  for (int off = 1; off < 256; off <<= 1) {
    int x = 0;
    if (t >= off) x = sdata[t - off];
    __syncthreads();
    if (t >= off) sdata[t] += x;
    __syncthreads();
  }
  if (t == 255) bsums[blockIdx.x] = sdata[255];
  int run = (t > 0) ? sdata[t - 1] : 0;
#pragma unroll
  for (int j = 0; j < 4; ++j) {
    int idx = base + t * 4 + j;
    if (idx < n) part[idx] = run;
    run += v[j];
  }
}

__global__ void scan2_kernel(int* __restrict__ bsums, int nb) {
  __shared__ int sdata[256];
  int t = threadIdx.x;
  sdata[t] = (t < nb) ? bsums[t] : 0;
  __syncthreads();
  for (int off = 1; off < 256; off <<= 1) {
    int x = 0;
    if (t >= off) x = sdata[t - off];
    __syncthreads();
    if (t >= off) sdata[t] += x;
    __syncthreads();
  }
  if (t < nb) bsums[t] = (t > 0) ? sdata[t - 1] : 0;
}

__global__ void scan3_kernel(const int* __restrict__ part, const int* __restrict__ bsums,
                             int* __restrict__ rowptr, int* __restrict__ cursor,
                             int n, int Etot) {
  int i = blockIdx.x * blockDim.x + threadIdx.x;
  if (i < n) {
    int v = part[i] + bsums[i >> 10];
    rowptr[i] = v;
    cursor[i] = v;
  }
  if (i == 0) rowptr[n] = Etot;
}

__global__ void scatter_kernel(const int* __restrict__ src, const int* __restrict__ dst,
                               int* __restrict__ cursor, int* __restrict__ csr_src, int E) {
  int e = blockIdx.x * blockDim.x + threadIdx.x;
  if (e < E) {
    int pos = atomicAdd(&cursor[dst[e]], 1);
    csr_src[pos] = src[e];
  }
}

// ---------------- GEMM: C[M,Nc] = A[M,K] * B[K,Nc], f32 in, bf16 out ----------------
#define TBM 64
#define TBN 64
#define TBK 32

__global__ __launch_bounds__(256) void gemm_f32_kernel(
    const float* __restrict__ A, const float* __restrict__ B, bf16* __restrict__ C,
    int M, int K, int Nc) {
  __shared__ float As[TBK][TBM + 4];
  __shared__ float Bs[TBK][TBN + 4];
  int tid = threadIdx.x;
  int tx = tid & 15, ty = tid >> 4;
  int rowBase = blockIdx.y * TBM;
  int colBase = blockIdx.x * TBN;

  float acc[4][4] = {};

  int arow = tid >> 2;        // 0..63
  int ak = (tid & 3) * 8;     // 0,8,16,24
  int brow = tid >> 3;        // 0..31
  int bcol = (tid & 7) * 8;   // 0..56

  for (int k0 = 0; k0 < K; k0 += TBK) {
    {
      int r = rowBase + arow;
      float vals[8];
      if (r < M) {
        const float* ap = A + (size_t)r * K + k0 + ak;
        float4 u0 = *(const float4*)(ap);
        float4 u1 = *(const float4*)(ap + 4);
        vals[0] = u0.x; vals[1] = u0.y; vals[2] = u0.z; vals[3] = u0.w;
        vals[4] = u1.x; vals[5] = u1.y; vals[6] = u1.z; vals[7] = u1.w;
      } else {
#pragma unroll
        for (int j = 0; j < 8; ++j) vals[j] = 0.f;
      }
#pragma unroll
      for (int j = 0; j < 8; ++j) As[ak + j][arow] = vals[j];
    }
    {
      int kr = k0 + brow;
      const float* bp = B + (size_t)kr * Nc;
#pragma unroll
      for (int j = 0; j < 8; ++j) {
        int c = colBase + bcol + j;
        Bs[brow][bcol + j] = (c < Nc) ? bp[c] : 0.f;
      }
    }
    __syncthreads();
#pragma unroll
    for (int kk = 0; kk < TBK; ++kk) {
      float4 av = *(const float4*)&As[kk][ty * 4];
      float4 bv = *(const float4*)&Bs[kk][tx * 4];
      float a[4] = {av.x, av.y, av.z, av.w};
      float b[4] = {bv.x, bv.y, bv.z, bv.w};
#pragma unroll
      for (int i = 0; i < 4; ++i)
#pragma unroll
        for (int j = 0; j < 4; ++j) acc[i][j] += a[i] * b[j];
    }
    __syncthreads();
  }
#pragma unroll
  for (int i = 0; i < 4; ++i) {
    int r = rowBase + ty * 4 + i;
    if (r < M) {
#pragma unroll
      for (int j = 0; j < 4; ++j) {
        int c = colBase + tx * 4 + j;
        if (c < Nc) C[(size_t)r * Nc + c] = __float2bfloat16(acc[i][j]);
      }
    }
  }
}

// ---------------- el/er from bf16 feat ----------------
__global__ void elr_kernel(const bf16* __restrict__ feat, const float* __restrict__ al,
                           const float* __restrict__ ar, float* __restrict__ el,
                           float* __restrict__ er, int N, int Dh, int Fd) {
  int g = blockIdx.x * blockDim.x + threadIdx.x;
  if (g >= N * 4) return;
  int n = g >> 2, h = g & 3;
  const bf16* fp = feat + (size_t)n * Fd + h * Dh;
  float sl = 0.f, sr = 0.f;
  for (int d = 0; d < Dh; ++d) {
    float f = b2f(fp[d]);
    sl += f * al[h * Dh + d];
    sr += f * ar[h * Dh + d];
  }
  el[g] = sl;
  er[g] = sr;
}

// ---------------- per-edge unnormalized softmax numerators, CSR order ----------------
// one wave per dst node: pass1 per-head max; pass2 lane (e,h) tiling, 16 edges/iter
__global__ __launch_bounds__(256) void edgeexp_kernel(
    const int* __restrict__ rowptr, const int* __restrict__ csr_src,
    const float* __restrict__ el, const float* __restrict__ er,
    float* __restrict__ exw, int N) {
  int lane = threadIdx.x & 63;
  int v = blockIdx.x * 4 + (threadIdx.x >> 6);
  if (v >= N) return;
  float erh[4];
#pragma unroll
  for (int h = 0; h < 4; ++h) erh[h] = er[v * 4 + h];
  int r0 = rowptr[v], r1 = rowptr[v + 1];
  float m[4] = {-1e30f, -1e30f, -1e30f, -1e30f};
  for (int i = r0 + lane; i < r1; i += 64) {
    int s = csr_src[i];
#pragma unroll
    for (int h = 0; h < 4; ++h) {
      float e = el[s * 4 + h] + erh[h];
      e = (e > 0.f) ? e : NEG_SLOPE * e;
      m[h] = fmaxf(m[h], e);
    }
  }
#pragma unroll
  for (int off = 32; off > 0; off >>= 1) {
#pragma unroll
    for (int h = 0; h < 4; ++h) m[h] = fmaxf(m[h], __shfl_xor(m[h], off));
  }
  int hh = lane & 3;
  float mh = (hh == 0) ? m[0] : (hh == 1) ? m[1] : (hh == 2) ? m[2] : m[3];
  float eh = (hh == 0) ? erh[0] : (hh == 1) ? erh[1] : (hh == 2) ? erh[2] : erh[3];
  for (int i0 = r0; i0 < r1; i0 += 16) {
    int i = i0 + (lane >> 2);
    if (i < r1) {
      int s = csr_src[i];
      float e = el[s * 4 + hh] + eh;
      e = (e > 0.f) ? e : NEG_SLOPE * e;
      exw[(size_t)i * 4 + hh] = __expf(e - mh);
    }
  }
}

// ---------------- layer 1/2 aggregation: F=128, one wave per dst node ----------------
__global__ __launch_bounds__(256) void agg128_kernel(
    const int* __restrict__ rowptr, const int* __restrict__ csr_src,
    const bf16* __restrict__ feat, const float* __restrict__ exw,
    const float* __restrict__ bias, float* __restrict__ hout, int N) {
  int lane = threadIdx.x & 63;
  int v = blockIdx.x * 4 + (threadIdx.x >> 6);
  if (v >= N) return;
  int r0 = rowptr[v], r1 = rowptr[v + 1];
  int f0 = lane, f1 = lane + 64;
  int h0 = lane >> 5, h1 = 2 + (lane >> 5);
  float acc0 = 0.f, acc1 = 0.f, den0 = 0.f, den1 = 0.f;
  for (int i = r0; i < r1; ++i) {
    int s = csr_src[i];
    float x0 = exw[(size_t)i * 4 + h0];
    float x1 = exw[(size_t)i * 4 + h1];
    den0 += x0;
    den1 += x1;
    acc0 += x0 * b2f(feat[(size_t)s * 128 + f0]);
    acc1 += x1 * b2f(feat[(size_t)s * 128 + f1]);
  }
  float o0 = (den0 > 0.f) ? acc0 / den0 : 0.f;
  float o1 = (den1 > 0.f) ? acc1 / den1 : 0.f;
  o0 = fmaxf(o0 + bias[f0], 0.f);
  o1 = fmaxf(o1 + bias[f1], 0.f);
  hout[(size_t)v * 128 + f0] = o0;
  hout[(size_t)v * 128 + f1] = o1;
}

// ---------------- layer 3 aggregation + bias + head-mean + log_softmax ----------------
__global__ __launch_bounds__(256) void agg3_kernel(
    const int* __restrict__ rowptr, const int* __restrict__ csr_src,
    const bf16* __restrict__ feat, const float* __restrict__ exw,
    const float* __restrict__ bias, float* __restrict__ out, int N) {
  __shared__ float sv[4][188];
  int lane = threadIdx.x & 63;
  int w = threadIdx.x >> 6;
  int v = blockIdx.x * 4 + w;
  bool valid = (v < N);
  int r0 = 0, r1 = 0;
  if (valid) {
    r0 = rowptr[v];
    r1 = rowptr[v + 1];
  }
  int f0 = lane, f1 = lane + 64, f2 = lane + 128;
  bool has2 = (f2 < 188);
  int h0 = f0 / 47, h1 = f1 / 47, h2 = has2 ? (f2 / 47) : 3;
  float acc0 = 0.f, acc1 = 0.f, acc2 = 0.f;
  float den0 = 0.f, den1 = 0.f, den2 = 0.f;
  for (int i = r0; i < r1; ++i) {
    int s = csr_src[i];
    float x0 = exw[(size_t)i * 4 + h0];
    float x1 = exw[(size_t)i * 4 + h1];
    float x2 = exw[(size_t)i * 4 + h2];
    den0 += x0;
    den1 += x1;
    den2 += x2;
    acc0 += x0 * b2f(feat[(size_t)s * 188 + f0]);
    acc1 += x1 * b2f(feat[(size_t)s * 188 + f1]);
    if (has2) acc2 += x2 * b2f(feat[(size_t)s * 188 + f2]);
  }
  float o0 = ((den0 > 0.f) ? acc0 / den0 : 0.f) + bias[f0];
  float o1 = ((den1 > 0.f) ? acc1 / den1 : 0.f) + bias[f1];
  float o2 = has2 ? (((den2 > 0.f) ? acc2 / den2 : 0.f) + bias[f2]) : 0.f;
  if (valid) {
    sv[w][f0] = o0;
    sv[w][f1] = o1;
    if (has2) sv[w][f2] = o2;
  }
  __syncthreads();
  float val = -1e30f;
  if (valid && lane < 47)
    val = 0.25f * (sv[w][lane] + sv[w][47 + lane] + sv[w][94 + lane] + sv[w][141 + lane]);
  float mx = val;
#pragma unroll
  for (int off = 32; off > 0; off >>= 1) mx = fmaxf(mx, __shfl_xor(mx, off));
  float ex = (lane < 47) ? __expf(val - mx) : 0.f;
  float sum = ex;
#pragma unroll
  for (int off = 32; off > 0; off >>= 1) sum += __shfl_xor(sum, off);
  float res = val - mx - logf(sum);
  if (valid && lane < 47) out[(size_t)v * 47 + lane] = res;
}

// ---------------- host orchestration ----------------
extern "C" void kernel_launch(void* const* d_in, const int* in_sizes, int n_in,
                              void* d_out, int out_size, void* d_ws, size_t ws_size,
                              hipStream_t stream) {
  const int N = 100000, E = 1600000, IN = 256;
  const int F = 128;   // H*D
  const int F3 = 188;  // H*C

  const float* x = (const float*)d_in[0];
  const int* src = (const int*)d_in[1];
  const int* dst = (const int*)d_in[2];
  const float* W1 = (const float*)d_in[3];
  const float* al1 = (const float*)d_in[4];
  const float* ar1 = (const float*)d_in[5];
  const float* b1 = (const float*)d_in[6];
  const float* W2 = (const float*)d_in[7];
  const float* al2 = (const float*)d_in[8];
  const float* ar2 = (const float*)d_in[9];
  const float* b2 = (const float*)d_in[10];
  const float* W3 = (const float*)d_in[11];
  const float* al3 = (const float*)d_in[12];
  const float* ar3 = (const float*)d_in[13];
  const float* b3 = (const float*)d_in[14];

  char* p = (char*)d_ws;
  auto alloc = [&](size_t bytes) -> char* {
    char* r = p;
    p += (bytes + 255) & ~(size_t)255;
    return r;
  };
  bf16* feat = (bf16*)alloc((size_t)N * F3 * sizeof(bf16));    // GEMM out per layer (bf16)
  float* hbuf = (float*)alloc((size_t)N * F * sizeof(float));  // aggregated hidden (f32)
  float* el = (float*)alloc((size_t)N * 4 * sizeof(float));
  float* er = (float*)alloc((size_t)N * 4 * sizeof(float));
  float* exw = (float*)alloc((size_t)E * 4 * sizeof(float));   // per-edge softmax numerators
  int* deg = (int*)alloc((size_t)N * sizeof(int));
  int* part = (int*)alloc((size_t)N * sizeof(int));
  int* bsums = (int*)alloc(256 * sizeof(int));
  int* rowptr = (int*)alloc((size_t)(N + 1) * sizeof(int));
  int* cursor = (int*)alloc((size_t)N * sizeof(int));
  int* csr_src = (int*)alloc((size_t)E * sizeof(int));

  // ---- CSR build (graph identical across layers) ----
  zero_int_kernel<<<(N + 255) / 256, 256, 0, stream>>>(deg, N);
  hist_kernel<<<(E + 255) / 256, 256, 0, stream>>>(dst, deg, E);
  int nb = (N + 1023) / 1024;  // 98
  scan1_kernel<<<nb, 256, 0, stream>>>(deg, part, bsums, N);
  scan2_kernel<<<1, 256, 0, stream>>>(bsums, nb);
  scan3_kernel<<<(N + 255) / 256, 256, 0, stream>>>(part, bsums, rowptr, cursor, N, E);
  scatter_kernel<<<(E + 255) / 256, 256, 0, stream>>>(src, dst, cursor, csr_src, E);

  int rowBlocks = (N + TBM - 1) / TBM;  // 1563
  int nodeBlocks = (N + 3) / 4;

  // ---- layer 1: IN=256 -> 128 ----
  gemm_f32_kernel<<<dim3(F / TBN, rowBlocks), 256, 0, stream>>>(x, W1, feat, N, IN, F);
  elr_kernel<<<(N * 4 + 255) / 256, 256, 0, stream>>>(feat, al1, ar1, el, er, N, 32, F);
  edgeexp_kernel<<<nodeBlocks, 256, 0, stream>>>(rowptr, csr_src, el, er, exw, N);
  agg128_kernel<<<nodeBlocks, 256, 0, stream>>>(rowptr, csr_src, feat, exw, b1, hbuf, N);

  // ---- layer 2: 128 -> 128 ----
  gemm_f32_kernel<<<dim3(F / TBN, rowBlocks), 256, 0, stream>>>(hbuf, W2, feat, N, F, F);
  elr_kernel<<<(N * 4 + 255) / 256, 256, 0, stream>>>(feat, al2, ar2, el, er, N, 32, F);
  edgeexp_kernel<<<nodeBlocks, 256, 0, stream>>>(rowptr, csr_src, el, er, exw, N);
  agg128_kernel<<<nodeBlocks, 256, 0, stream>>>(rowptr, csr_src, feat, exw, b2, hbuf, N);

  // ---- layer 3: 128 -> 188, fused epilogue ----
  gemm_f32_kernel<<<dim3((F3 + TBN - 1) / TBN, rowBlocks), 256, 0, stream>>>(hbuf, W3, feat, N, F, F3);
  elr_kernel<<<(N * 4 + 255) / 256, 256, 0, stream>>>(feat, al3, ar3, el, er, N, 47, F3);
  edgeexp_kernel<<<nodeBlocks, 256, 0, stream>>>(rowptr, csr_src, el, er, exw, N);
  agg3_kernel<<<nodeBlocks, 256, 0, stream>>>(rowptr, csr_src, feat, exw, b3,
                                              (float*)d_out, N);
}

// Round 5
// 1184.890 us; speedup vs baseline: 1.3194x; 1.1518x over previous
//
#include <hip/hip_runtime.h>
#include <hip/hip_bf16.h>

typedef unsigned short ushort;
typedef unsigned int uint;
typedef __attribute__((ext_vector_type(8))) short short8;
typedef __attribute__((ext_vector_type(4))) float floatx4;

#define NEG_SLOPE 0.2f

__device__ __forceinline__ float bu2f(ushort u) {
  uint t = ((uint)u) << 16;
  return __uint_as_float(t);
}
__device__ __forceinline__ ushort f2bu(float f) {
  __hip_bfloat16 h = __float2bfloat16(f);
  return *(ushort*)&h;
}
__device__ __forceinline__ float lo2f(uint u) { return __uint_as_float(u << 16); }
__device__ __forceinline__ float hi2f(uint u) { return __uint_as_float(u & 0xffff0000u); }

// ---------------- CSR build ----------------
__global__ void zero_int_kernel(int* __restrict__ p, int n) {
  int i = blockIdx.x * blockDim.x + threadIdx.x;
  if (i < n) p[i] = 0;
}

__global__ void hist_kernel(const int* __restrict__ dst, int* __restrict__ deg, int E) {
  int e = blockIdx.x * blockDim.x + threadIdx.x;
  if (e < E) atomicAdd(&deg[dst[e]], 1);
}

__global__ void scan1_kernel(const int* __restrict__ deg, int* __restrict__ part,
                             int* __restrict__ bsums, int n) {
  __shared__ int sdata[256];
  int t = threadIdx.x;
  int base = blockIdx.x * 1024;
  int v[4]; int s = 0;
#pragma unroll
  for (int j = 0; j < 4; ++j) {
    int idx = base + t * 4 + j;
    v[j] = (idx < n) ? deg[idx] : 0;
    s += v[j];
  }
  sdata[t] = s;
  __syncthreads();
  for (int off = 1; off < 256; off <<= 1) {
    int x = 0;
    if (t >= off) x = sdata[t - off];
    __syncthreads();
    if (t >= off) sdata[t] += x;
    __syncthreads();
  }
  if (t == 255) bsums[blockIdx.x] = sdata[255];
  int run = (t > 0) ? sdata[t - 1] : 0;
#pragma unroll
  for (int j = 0; j < 4; ++j) {
    int idx = base + t * 4 + j;
    if (idx < n) part[idx] = run;
    run += v[j];
  }
}

__global__ void scan2_kernel(int* __restrict__ bsums, int nb) {
  __shared__ int sdata[256];
  int t = threadIdx.x;
  sdata[t] = (t < nb) ? bsums[t] : 0;
  __syncthreads();
  for (int off = 1; off < 256; off <<= 1) {
    int x = 0;
    if (t >= off) x = sdata[t - off];
    __syncthreads();
    if (t >= off) sdata[t] += x;
    __syncthreads();
  }
  if (t < nb) bsums[t] = (t > 0) ? sdata[t - 1] : 0;
}

__global__ void scan3_kernel(const int* __restrict__ part, const int* __restrict__ bsums,
                             int* __restrict__ rowptr, int* __restrict__ cursor,
                             int n, int Etot) {
  int i = blockIdx.x * blockDim.x + threadIdx.x;
  if (i < n) {
    int v = part[i] + bsums[i >> 10];
    rowptr[i] = v;
    cursor[i] = v;
  }
  if (i == 0) rowptr[n] = Etot;
}

__global__ void scatter_kernel(const int* __restrict__ src, const int* __restrict__ dst,
                               int* __restrict__ cursor, int* __restrict__ csr_src, int E) {
  int e = blockIdx.x * blockDim.x + threadIdx.x;
  if (e < E) {
    int pos = atomicAdd(&cursor[dst[e]], 1);
    csr_src[pos] = src[e];
  }
}

// ---------------- splits ----------------
// x -> hi/lo bf16 pair (4 elems/thread)
__global__ void splitx_kernel(const float* __restrict__ x, ushort* __restrict__ xhi,
                              ushort* __restrict__ xlo, int n) {
  int base = (blockIdx.x * blockDim.x + threadIdx.x) * 4;
  if (base >= n) return;
  float4 a = *(const float4*)(x + base);
  float v[4] = {a.x, a.y, a.z, a.w};
  ushort hi[4], lo[4];
#pragma unroll
  for (int j = 0; j < 4; ++j) {
    hi[j] = f2bu(v[j]);
    lo[j] = f2bu(v[j] - bu2f(hi[j]));
  }
  uint2 ho, loo;
  ho.x = (uint)hi[0] | ((uint)hi[1] << 16);
  ho.y = (uint)hi[2] | ((uint)hi[3] << 16);
  loo.x = (uint)lo[0] | ((uint)lo[1] << 16);
  loo.y = (uint)lo[2] | ((uint)lo[3] << 16);
  *(uint2*)(xhi + base) = ho;
  *(uint2*)(xlo + base) = loo;
}

// Wt[n][k] = split(W[k][n])
__global__ void splitW_kernel(const float* __restrict__ W, ushort* __restrict__ WtH,
                              ushort* __restrict__ WtL, int K, int Nc) {
  int idx = blockIdx.x * blockDim.x + threadIdx.x;
  if (idx >= K * Nc) return;
  int n = idx / K, k = idx - n * K;
  float w = W[(size_t)k * Nc + n];
  ushort hi = f2bu(w);
  WtH[idx] = hi;
  WtL[idx] = f2bu(w - bu2f(hi));
}

// ---------------- split-bf16 MFMA GEMM: C = A * Wt^T, ~f32 precision ----------------
// A given as hi/lo bf16, Wt (row-major [Nc][K]) as hi/lo bf16.
// acc += Ah*Bh + Ah*Bl + Al*Bh  (lo*lo dropped, ~2^-18 relative)
#define GBM 128
#define GBN 64
#define GBK 32
#define SA 40

__global__ __launch_bounds__(256) void gemm_split_kernel(
    const ushort* __restrict__ Ah, const ushort* __restrict__ Al,
    const ushort* __restrict__ Bh, const ushort* __restrict__ Bl,
    ushort* __restrict__ C, int M, int K, int Nc) {
  __shared__ ushort AsH[GBM * SA];
  __shared__ ushort AsL[GBM * SA];
  __shared__ ushort BsH[GBN * SA];
  __shared__ ushort BsL[GBN * SA];
  int tid = threadIdx.x;
  int lane = tid & 63;
  int wave = tid >> 6;
  int wm = wave & 1, wn = wave >> 1;
  int rowBase = blockIdx.y * GBM;
  int colBase = blockIdx.x * GBN;
  int q = lane >> 4;   // quad
  int ln = lane & 15;

  floatx4 acc[4][2] = {};

  for (int k0 = 0; k0 < K; k0 += GBK) {
    // stage A: 128 rows x 32 k, hi+lo
#pragma unroll
    for (int it = 0; it < 2; ++it) {
      int i = tid + it * 256;
      int r = i >> 2, seg = i & 3;
      int grow = rowBase + r;
      uint4 vh = {0u, 0u, 0u, 0u}, vl = {0u, 0u, 0u, 0u};
      if (grow < M) {
        size_t off = (size_t)grow * K + k0 + seg * 8;
        vh = *(const uint4*)(Ah + off);
        vl = *(const uint4*)(Al + off);
      }
      *(uint4*)&AsH[r * SA + seg * 8] = vh;
      *(uint4*)&AsL[r * SA + seg * 8] = vl;
    }
    // stage B: 64 cols x 32 k, hi+lo
    {
      int n = tid >> 2, seg = tid & 3;
      int gcol = colBase + n;
      uint4 vh = {0u, 0u, 0u, 0u}, vl = {0u, 0u, 0u, 0u};
      if (gcol < Nc) {
        size_t off = (size_t)gcol * K + k0 + seg * 8;
        vh = *(const uint4*)(Bh + off);
        vl = *(const uint4*)(Bl + off);
      }
      *(uint4*)&BsH[n * SA + seg * 8] = vh;
      *(uint4*)&BsL[n * SA + seg * 8] = vl;
    }
    __syncthreads();
    short8 afH[4], afL[4], bfH[2], bfL[2];
#pragma unroll
    for (int mt = 0; mt < 4; ++mt) {
      int r = (wm * 64 + mt * 16 + ln) * SA + q * 8;
      afH[mt] = *(const short8*)&AsH[r];
      afL[mt] = *(const short8*)&AsL[r];
    }
#pragma unroll
    for (int nt = 0; nt < 2; ++nt) {
      int r = (wn * 32 + nt * 16 + ln) * SA + q * 8;
      bfH[nt] = *(const short8*)&BsH[r];
      bfL[nt] = *(const short8*)&BsL[r];
    }
#pragma unroll
    for (int mt = 0; mt < 4; ++mt)
#pragma unroll
      for (int nt = 0; nt < 2; ++nt) {
        acc[mt][nt] = __builtin_amdgcn_mfma_f32_16x16x32_bf16(afH[mt], bfH[nt], acc[mt][nt], 0, 0, 0);
        acc[mt][nt] = __builtin_amdgcn_mfma_f32_16x16x32_bf16(afH[mt], bfL[nt], acc[mt][nt], 0, 0, 0);
        acc[mt][nt] = __builtin_amdgcn_mfma_f32_16x16x32_bf16(afL[mt], bfH[nt], acc[mt][nt], 0, 0, 0);
      }
    __syncthreads();
  }
#pragma unroll
  for (int mt = 0; mt < 4; ++mt) {
#pragma unroll
    for (int nt = 0; nt < 2; ++nt) {
      int col = colBase + wn * 32 + nt * 16 + ln;
      if (col < Nc) {
#pragma unroll
        for (int r = 0; r < 4; ++r) {
          int row = rowBase + wm * 64 + mt * 16 + q * 4 + r;
          if (row < M) C[(size_t)row * Nc + col] = f2bu(acc[mt][nt][r]);
        }
      }
    }
  }
}

// ---------------- el/er from bf16(bits) feat ----------------
__global__ void elr_kernel(const ushort* __restrict__ feat, const float* __restrict__ al,
                           const float* __restrict__ ar, float* __restrict__ el,
                           float* __restrict__ er, int N, int Dh, int Fd) {
  int g = blockIdx.x * blockDim.x + threadIdx.x;
  if (g >= N * 4) return;
  int n = g >> 2, h = g & 3;
  const ushort* fp = feat + (size_t)n * Fd + h * Dh;
  float sl = 0.f, sr = 0.f;
  for (int d = 0; d < Dh; ++d) {
    float f = bu2f(fp[d]);
    sl += f * al[h * Dh + d];
    sr += f * ar[h * Dh + d];
  }
  el[g] = sl;
  er[g] = sr;
}

// ---------------- per-edge softmax numerators, CSR order ----------------
__global__ __launch_bounds__(256) void edgeexp_kernel(
    const int* __restrict__ rowptr, const int* __restrict__ csr_src,
    const float* __restrict__ el, const float* __restrict__ er,
    float* __restrict__ exw, int N) {
  int lane = threadIdx.x & 63;
  int v = blockIdx.x * 4 + (threadIdx.x >> 6);
  if (v >= N) return;
  float erh[4];
#pragma unroll
  for (int h = 0; h < 4; ++h) erh[h] = er[v * 4 + h];
  int r0 = rowptr[v], r1 = rowptr[v + 1];
  float m[4] = {-1e30f, -1e30f, -1e30f, -1e30f};
  for (int i = r0 + lane; i < r1; i += 64) {
    int s = csr_src[i];
#pragma unroll
    for (int h = 0; h < 4; ++h) {
      float e = el[s * 4 + h] + erh[h];
      e = (e > 0.f) ? e : NEG_SLOPE * e;
      m[h] = fmaxf(m[h], e);
    }
  }
#pragma unroll
  for (int off = 32; off > 0; off >>= 1) {
#pragma unroll
    for (int h = 0; h < 4; ++h) m[h] = fmaxf(m[h], __shfl_xor(m[h], off));
  }
  int hh = lane & 3;
  float mh = (hh == 0) ? m[0] : (hh == 1) ? m[1] : (hh == 2) ? m[2] : m[3];
  float eh = (hh == 0) ? erh[0] : (hh == 1) ? erh[1] : (hh == 2) ? erh[2] : erh[3];
  for (int i0 = r0; i0 < r1; i0 += 16) {
    int i = i0 + (lane >> 2);
    if (i < r1) {
      int s = csr_src[i];
      float e = el[s * 4 + hh] + eh;
      e = (e > 0.f) ? e : NEG_SLOPE * e;
      exw[(size_t)i * 4 + hh] = __expf(e - mh);
    }
  }
}

// ---------------- layer 1/2 aggregation: F=128, one wave per node, hi/lo h out ----------------
__global__ __launch_bounds__(256) void agg128_kernel(
    const int* __restrict__ rowptr, const int* __restrict__ csr_src,
    const ushort* __restrict__ feat, const float* __restrict__ exw,
    const float* __restrict__ bias, ushort* __restrict__ hhi,
    ushort* __restrict__ hlo, int N) {
  int lane = threadIdx.x & 63;
  int v = blockIdx.x * 4 + (threadIdx.x >> 6);
  if (v >= N) return;
  int r0 = rowptr[v], r1 = rowptr[v + 1];
  int h = lane >> 4;  // features 2l,2l+1 -> head (2l)>>5 = lane>>4
  const uint* fb = (const uint*)feat;
  float a0 = 0.f, a1 = 0.f, den = 0.f;
  int i = r0;
  for (; i + 2 <= r1; i += 2) {
    int s0 = csr_src[i], s1 = csr_src[i + 1];
    float xa = exw[(size_t)i * 4 + h];
    float xb = exw[(size_t)(i + 1) * 4 + h];
    uint u0 = fb[(size_t)s0 * 64 + lane];
    uint u1 = fb[(size_t)s1 * 64 + lane];
    den += xa + xb;
    a0 += xa * lo2f(u0) + xb * lo2f(u1);
    a1 += xa * hi2f(u0) + xb * hi2f(u1);
  }
  if (i < r1) {
    int s0 = csr_src[i];
    float xa = exw[(size_t)i * 4 + h];
    uint u0 = fb[(size_t)s0 * 64 + lane];
    den += xa;
    a0 += xa * lo2f(u0);
    a1 += xa * hi2f(u0);
  }
  float o0 = (den > 0.f) ? a0 / den : 0.f;
  float o1 = (den > 0.f) ? a1 / den : 0.f;
  o0 = fmaxf(o0 + bias[2 * lane], 0.f);
  o1 = fmaxf(o1 + bias[2 * lane + 1], 0.f);
  ushort h0 = f2bu(o0), h1 = f2bu(o1);
  ushort l0 = f2bu(o0 - bu2f(h0)), l1 = f2bu(o1 - bu2f(h1));
  ((uint*)hhi)[(size_t)v * 64 + lane] = (uint)h0 | ((uint)h1 << 16);
  ((uint*)hlo)[(size_t)v * 64 + lane] = (uint)l0 | ((uint)l1 << 16);
}

// ---------------- layer 3 aggregation + bias + head-mean + log_softmax ----------------
__global__ __launch_bounds__(256) void agg3_kernel(
    const int* __restrict__ rowptr, const int* __restrict__ csr_src,
    const ushort* __restrict__ feat, const float* __restrict__ exw,
    const float* __restrict__ bias, float* __restrict__ out, int N) {
  __shared__ float sv[4][188];
  int lane = threadIdx.x & 63;
  int w = threadIdx.x >> 6;
  int v = blockIdx.x * 4 + w;
  bool valid = (v < N);
  int r0 = 0, r1 = 0;
  if (valid) {
    r0 = rowptr[v];
    r1 = rowptr[v + 1];
  }
  int fa = 2 * lane, fbi = 2 * lane + 1;
  int fc = 128 + 2 * lane, fd = 129 + 2 * lane;
  bool hasC = (fd < 188);  // lanes 0..29
  int ha = fa / 47, hb = fbi / 47;
  int hc = hasC ? fc / 47 : 3, hd = hasC ? fd / 47 : 3;
  const uint* fpb = (const uint*)feat;  // feat row: 94 uints
  float aa = 0.f, ab = 0.f, ac = 0.f, ad = 0.f;
  float da = 0.f, db = 0.f, dc = 0.f, dd = 0.f;
  for (int i = r0; i < r1; ++i) {
    int s = csr_src[i];
    const float* xw = exw + (size_t)i * 4;
    float xa = xw[ha], xb = xw[hb];
    uint u0 = fpb[(size_t)s * 94 + lane];
    da += xa; db += xb;
    aa += xa * lo2f(u0);
    ab += xb * hi2f(u0);
    if (hasC) {
      float xc = xw[hc], xd = xw[hd];
      uint u1 = fpb[(size_t)s * 94 + 64 + lane];  // features 128+2l,129+2l
      dc += xc; dd += xd;
      ac += xc * lo2f(u1);
      ad += xd * hi2f(u1);
    }
  }
  float oa = ((da > 0.f) ? aa / da : 0.f) + bias[fa];
  float ob = ((db > 0.f) ? ab / db : 0.f) + bias[fbi];
  if (valid) {
    sv[w][fa] = oa;
    sv[w][fbi] = ob;
    if (hasC) {
      float oc = ((dc > 0.f) ? ac / dc : 0.f) + bias[fc];
      float od = ((dd > 0.f) ? ad / dd : 0.f) + bias[fd];
      sv[w][fc] = oc;
      sv[w][fd] = od;
    }
  }
  __syncthreads();
  float val = -1e30f;
  if (valid && lane < 47)
    val = 0.25f * (sv[w][lane] + sv[w][47 + lane] + sv[w][94 + lane] + sv[w][141 + lane]);
  float mx = val;
#pragma unroll
  for (int off = 32; off > 0; off >>= 1) mx = fmaxf(mx, __shfl_xor(mx, off));
  float ex = (lane < 47) ? __expf(val - mx) : 0.f;
  float sum = ex;
#pragma unroll
  for (int off = 32; off > 0; off >>= 1) sum += __shfl_xor(sum, off);
  float res = val - mx - logf(sum);
  if (valid && lane < 47) out[(size_t)v * 47 + lane] = res;
}

// ---------------- host orchestration ----------------
extern "C" void kernel_launch(void* const* d_in, const int* in_sizes, int n_in,
                              void* d_out, int out_size, void* d_ws, size_t ws_size,
                              hipStream_t stream) {
  const int N = 100000, E = 1600000, IN = 256;
  const int F = 128;   // H*D
  const int F3 = 188;  // H*C

  const float* x = (const float*)d_in[0];
  const int* src = (const int*)d_in[1];
  const int* dst = (const int*)d_in[2];
  const float* W1 = (const float*)d_in[3];
  const float* al1 = (const float*)d_in[4];
  const float* ar1 = (const float*)d_in[5];
  const float* b1 = (const float*)d_in[6];
  const float* W2 = (const float*)d_in[7];
  const float* al2 = (const float*)d_in[8];
  const float* ar2 = (const float*)d_in[9];
  const float* b2 = (const float*)d_in[10];
  const float* W3 = (const float*)d_in[11];
  const float* al3 = (const float*)d_in[12];
  const float* ar3 = (const float*)d_in[13];
  const float* b3 = (const float*)d_in[14];

  char* p = (char*)d_ws;
  auto alloc = [&](size_t bytes) -> char* {
    char* r = p;
    p += (bytes + 255) & ~(size_t)255;
    return r;
  };
  ushort* xhi = (ushort*)alloc((size_t)N * IN * sizeof(ushort));
  ushort* xlo = (ushort*)alloc((size_t)N * IN * sizeof(ushort));
  ushort* feat = (ushort*)alloc((size_t)N * F3 * sizeof(ushort));
  ushort* Wt1h = (ushort*)alloc((size_t)F * IN * sizeof(ushort));
  ushort* Wt1l = (ushort*)alloc((size_t)F * IN * sizeof(ushort));
  ushort* Wt2h = (ushort*)alloc((size_t)F * F * sizeof(ushort));
  ushort* Wt2l = (ushort*)alloc((size_t)F * F * sizeof(ushort));
  ushort* Wt3h = (ushort*)alloc((size_t)F3 * F * sizeof(ushort));
  ushort* Wt3l = (ushort*)alloc((size_t)F3 * F * sizeof(ushort));
  float* el = (float*)alloc((size_t)N * 4 * sizeof(float));
  float* er = (float*)alloc((size_t)N * 4 * sizeof(float));
  float* exw = (float*)alloc((size_t)E * 4 * sizeof(float));
  int* deg = (int*)alloc((size_t)N * sizeof(int));
  int* part = (int*)alloc((size_t)N * sizeof(int));
  int* bsums = (int*)alloc(256 * sizeof(int));
  int* rowptr = (int*)alloc((size_t)(N + 1) * sizeof(int));
  int* cursor = (int*)alloc((size_t)N * sizeof(int));
  int* csr_src = (int*)alloc((size_t)E * sizeof(int));

  // h (layers 2/3 input) aliases the x split buffers — x is consumed by the
  // layer-1 GEMM before agg128 overwrites these (single-stream ordering).
  ushort* hhi = xhi;
  ushort* hlo = xlo;

  // ---- CSR build ----
  zero_int_kernel<<<(N + 255) / 256, 256, 0, stream>>>(deg, N);
  hist_kernel<<<(E + 255) / 256, 256, 0, stream>>>(dst, deg, E);
  int nb = (N + 1023) / 1024;
  scan1_kernel<<<nb, 256, 0, stream>>>(deg, part, bsums, N);
  scan2_kernel<<<1, 256, 0, stream>>>(bsums, nb);
  scan3_kernel<<<(N + 255) / 256, 256, 0, stream>>>(part, bsums, rowptr, cursor, N, E);
  scatter_kernel<<<(E + 255) / 256, 256, 0, stream>>>(src, dst, cursor, csr_src, E);

  // ---- splits ----
  splitx_kernel<<<(N * IN / 4 + 255) / 256, 256, 0, stream>>>(x, xhi, xlo, N * IN);
  splitW_kernel<<<(IN * F + 255) / 256, 256, 0, stream>>>(W1, Wt1h, Wt1l, IN, F);
  splitW_kernel<<<(F * F + 255) / 256, 256, 0, stream>>>(W2, Wt2h, Wt2l, F, F);
  splitW_kernel<<<(F * F3 + 255) / 256, 256, 0, stream>>>(W3, Wt3h, Wt3l, F, F3);

  int rowBlocks = (N + GBM - 1) / GBM;  // 782
  int nodeBlocks = (N + 3) / 4;

  // ---- layer 1: IN=256 -> 128 ----
  gemm_split_kernel<<<dim3(F / GBN, rowBlocks), 256, 0, stream>>>(
      xhi, xlo, Wt1h, Wt1l, feat, N, IN, F);
  elr_kernel<<<(N * 4 + 255) / 256, 256, 0, stream>>>(feat, al1, ar1, el, er, N, 32, F);
  edgeexp_kernel<<<nodeBlocks, 256, 0, stream>>>(rowptr, csr_src, el, er, exw, N);
  agg128_kernel<<<nodeBlocks, 256, 0, stream>>>(rowptr, csr_src, feat, exw, b1, hhi, hlo, N);

  // ---- layer 2: 128 -> 128 ----
  gemm_split_kernel<<<dim3(F / GBN, rowBlocks), 256, 0, stream>>>(
      hhi, hlo, Wt2h, Wt2l, feat, N, F, F);
  elr_kernel<<<(N * 4 + 255) / 256, 256, 0, stream>>>(feat, al2, ar2, el, er, N, 32, F);
  edgeexp_kernel<<<nodeBlocks, 256, 0, stream>>>(rowptr, csr_src, el, er, exw, N);
  agg128_kernel<<<nodeBlocks, 256, 0, stream>>>(rowptr, csr_src, feat, exw, b2, hhi, hlo, N);

  // ---- layer 3: 128 -> 188, fused epilogue ----
  gemm_split_kernel<<<dim3((F3 + GBN - 1) / GBN, rowBlocks), 256, 0, stream>>>(
      hhi, hlo, Wt3h, Wt3l, feat, N, F, F3);
  elr_kernel<<<(N * 4 + 255) / 256, 256, 0, stream>>>(feat, al3, ar3, el, er, N, 47, F3);
  edgeexp_kernel<<<nodeBlocks, 256, 0, stream>>>(rowptr, csr_src, el, er, exw, N);
  agg3_kernel<<<nodeBlocks, 256, 0, stream>>>(rowptr, csr_src, feat, exw, b3,
                                              (float*)d_out, N);
}

// Round 6
// 1112.044 us; speedup vs baseline: 1.4059x; 1.0655x over previous
//
#include <hip/hip_runtime.h>
#include <hip/hip_bf16.h>

typedef unsigned short ushort;
typedef unsigned int uint;
typedef __attribute__((ext_vector_type(8))) short short8;
typedef __attribute__((ext_vector_type(4))) float floatx4;

#define NEG_SLOPE 0.2f

__device__ __forceinline__ float bu2f(ushort u) {
  uint t = ((uint)u) << 16;
  return __uint_as_float(t);
}
__device__ __forceinline__ ushort f2bu(float f) {
  __hip_bfloat16 h = __float2bfloat16(f);
  return *(ushort*)&h;
}
__device__ __forceinline__ float lo2f(uint u) { return __uint_as_float(u << 16); }
__device__ __forceinline__ float hi2f(uint u) { return __uint_as_float(u & 0xffff0000u); }
__device__ __forceinline__ float lrelu(float e) { return (e > 0.f) ? e : NEG_SLOPE * e; }

// ---------------- CSR build ----------------
__global__ void zero_int_kernel(int* __restrict__ p, int n) {
  int i = blockIdx.x * blockDim.x + threadIdx.x;
  if (i < n) p[i] = 0;
}

__global__ void hist_kernel(const int* __restrict__ dst, int* __restrict__ deg, int E) {
  int e = blockIdx.x * blockDim.x + threadIdx.x;
  if (e < E) atomicAdd(&deg[dst[e]], 1);
}

__global__ void scan1_kernel(const int* __restrict__ deg, int* __restrict__ part,
                             int* __restrict__ bsums, int n) {
  __shared__ int sdata[256];
  int t = threadIdx.x;
  int base = blockIdx.x * 1024;
  int v[4]; int s = 0;
#pragma unroll
  for (int j = 0; j < 4; ++j) {
    int idx = base + t * 4 + j;
    v[j] = (idx < n) ? deg[idx] : 0;
    s += v[j];
  }
  sdata[t] = s;
  __syncthreads();
  for (int off = 1; off < 256; off <<= 1) {
    int x = 0;
    if (t >= off) x = sdata[t - off];
    __syncthreads();
    if (t >= off) sdata[t] += x;
    __syncthreads();
  }
  if (t == 255) bsums[blockIdx.x] = sdata[255];
  int run = (t > 0) ? sdata[t - 1] : 0;
#pragma unroll
  for (int j = 0; j < 4; ++j) {
    int idx = base + t * 4 + j;
    if (idx < n) part[idx] = run;
    run += v[j];
  }
}

__global__ void scan2_kernel(int* __restrict__ bsums, int nb) {
  __shared__ int sdata[256];
  int t = threadIdx.x;
  sdata[t] = (t < nb) ? bsums[t] : 0;
  __syncthreads();
  for (int off = 1; off < 256; off <<= 1) {
    int x = 0;
    if (t >= off) x = sdata[t - off];
    __syncthreads();
    if (t >= off) sdata[t] += x;
    __syncthreads();
  }
  if (t < nb) bsums[t] = (t > 0) ? sdata[t - 1] : 0;
}

__global__ void scan3_kernel(const int* __restrict__ part, const int* __restrict__ bsums,
                             int* __restrict__ rowptr, int* __restrict__ cursor,
                             int n, int Etot) {
  int i = blockIdx.x * blockDim.x + threadIdx.x;
  if (i < n) {
    int v = part[i] + bsums[i >> 10];
    rowptr[i] = v;
    cursor[i] = v;
  }
  if (i == 0) rowptr[n] = Etot;
}

__global__ void scatter_kernel(const int* __restrict__ src, const int* __restrict__ dst,
                               int* __restrict__ cursor, int* __restrict__ csr_src, int E) {
  int e = blockIdx.x * blockDim.x + threadIdx.x;
  if (e < E) {
    int pos = atomicAdd(&cursor[dst[e]], 1);
    csr_src[pos] = src[e];
  }
}

// ---------------- splits ----------------
__global__ void splitx_kernel(const float* __restrict__ x, ushort* __restrict__ xhi,
                              ushort* __restrict__ xlo, int n) {
  int base = (blockIdx.x * blockDim.x + threadIdx.x) * 4;
  if (base >= n) return;
  float4 a = *(const float4*)(x + base);
  float v[4] = {a.x, a.y, a.z, a.w};
  ushort hi[4], lo[4];
#pragma unroll
  for (int j = 0; j < 4; ++j) {
    hi[j] = f2bu(v[j]);
    lo[j] = f2bu(v[j] - bu2f(hi[j]));
  }
  uint2 ho, loo;
  ho.x = (uint)hi[0] | ((uint)hi[1] << 16);
  ho.y = (uint)hi[2] | ((uint)hi[3] << 16);
  loo.x = (uint)lo[0] | ((uint)lo[1] << 16);
  loo.y = (uint)lo[2] | ((uint)lo[3] << 16);
  *(uint2*)(xhi + base) = ho;
  *(uint2*)(xlo + base) = loo;
}

__global__ void splitW_kernel(const float* __restrict__ W, ushort* __restrict__ WtH,
                              ushort* __restrict__ WtL, int K, int Nc) {
  int idx = blockIdx.x * blockDim.x + threadIdx.x;
  if (idx >= K * Nc) return;
  int n = idx / K, k = idx - n * K;
  float w = W[(size_t)k * Nc + n];
  ushort hi = f2bu(w);
  WtH[idx] = hi;
  WtL[idx] = f2bu(w - bu2f(hi));
}

// ---------------- split-bf16 MFMA GEMM ----------------
#define GBM 128
#define GBN 64
#define GBK 32
#define SA 40

__global__ __launch_bounds__(256) void gemm_split_kernel(
    const ushort* __restrict__ Ah, const ushort* __restrict__ Al,
    const ushort* __restrict__ Bh, const ushort* __restrict__ Bl,
    ushort* __restrict__ C, int M, int K, int Nc) {
  __shared__ ushort AsH[GBM * SA];
  __shared__ ushort AsL[GBM * SA];
  __shared__ ushort BsH[GBN * SA];
  __shared__ ushort BsL[GBN * SA];
  int tid = threadIdx.x;
  int lane = tid & 63;
  int wave = tid >> 6;
  int wm = wave & 1, wn = wave >> 1;
  int rowBase = blockIdx.y * GBM;
  int colBase = blockIdx.x * GBN;
  int q = lane >> 4;
  int ln = lane & 15;

  floatx4 acc[4][2] = {};

  for (int k0 = 0; k0 < K; k0 += GBK) {
#pragma unroll
    for (int it = 0; it < 2; ++it) {
      int i = tid + it * 256;
      int r = i >> 2, seg = i & 3;
      int grow = rowBase + r;
      uint4 vh = {0u, 0u, 0u, 0u}, vl = {0u, 0u, 0u, 0u};
      if (grow < M) {
        size_t off = (size_t)grow * K + k0 + seg * 8;
        vh = *(const uint4*)(Ah + off);
        vl = *(const uint4*)(Al + off);
      }
      *(uint4*)&AsH[r * SA + seg * 8] = vh;
      *(uint4*)&AsL[r * SA + seg * 8] = vl;
    }
    {
      int n = tid >> 2, seg = tid & 3;
      int gcol = colBase + n;
      uint4 vh = {0u, 0u, 0u, 0u}, vl = {0u, 0u, 0u, 0u};
      if (gcol < Nc) {
        size_t off = (size_t)gcol * K + k0 + seg * 8;
        vh = *(const uint4*)(Bh + off);
        vl = *(const uint4*)(Bl + off);
      }
      *(uint4*)&BsH[n * SA + seg * 8] = vh;
      *(uint4*)&BsL[n * SA + seg * 8] = vl;
    }
    __syncthreads();
    short8 afH[4], afL[4], bfH[2], bfL[2];
#pragma unroll
    for (int mt = 0; mt < 4; ++mt) {
      int r = (wm * 64 + mt * 16 + ln) * SA + q * 8;
      afH[mt] = *(const short8*)&AsH[r];
      afL[mt] = *(const short8*)&AsL[r];
    }
#pragma unroll
    for (int nt = 0; nt < 2; ++nt) {
      int r = (wn * 32 + nt * 16 + ln) * SA + q * 8;
      bfH[nt] = *(const short8*)&BsH[r];
      bfL[nt] = *(const short8*)&BsL[r];
    }
#pragma unroll
    for (int mt = 0; mt < 4; ++mt)
#pragma unroll
      for (int nt = 0; nt < 2; ++nt) {
        acc[mt][nt] = __builtin_amdgcn_mfma_f32_16x16x32_bf16(afH[mt], bfH[nt], acc[mt][nt], 0, 0, 0);
        acc[mt][nt] = __builtin_amdgcn_mfma_f32_16x16x32_bf16(afH[mt], bfL[nt], acc[mt][nt], 0, 0, 0);
        acc[mt][nt] = __builtin_amdgcn_mfma_f32_16x16x32_bf16(afL[mt], bfH[nt], acc[mt][nt], 0, 0, 0);
      }
    __syncthreads();
  }
#pragma unroll
  for (int mt = 0; mt < 4; ++mt) {
#pragma unroll
    for (int nt = 0; nt < 2; ++nt) {
      int col = colBase + wn * 32 + nt * 16 + ln;
      if (col < Nc) {
#pragma unroll
        for (int r = 0; r < 4; ++r) {
          int row = rowBase + wm * 64 + mt * 16 + q * 4 + r;
          if (row < M) C[(size_t)row * Nc + col] = f2bu(acc[mt][nt][r]);
        }
      }
    }
  }
}

// ---------------- el/er from bf16(bits) feat ----------------
__global__ void elr_kernel(const ushort* __restrict__ feat, const float* __restrict__ al,
                           const float* __restrict__ ar, float* __restrict__ el,
                           float* __restrict__ er, int N, int Dh, int Fd) {
  int g = blockIdx.x * blockDim.x + threadIdx.x;
  if (g >= N * 4) return;
  int n = g >> 2, h = g & 3;
  const ushort* fp = feat + (size_t)n * Fd + h * Dh;
  float sl = 0.f, sr = 0.f;
  for (int d = 0; d < Dh; ++d) {
    float f = bu2f(fp[d]);
    sl += f * al[h * Dh + d];
    sr += f * ar[h * Dh + d];
  }
  el[g] = sl;
  er[g] = sr;
}

// ---------------- fused layer 1/2 aggregation (softmax inline), wave/node ----------------
__global__ __launch_bounds__(256) void agg128_kernel(
    const int* __restrict__ rowptr, const int* __restrict__ csr_src,
    const ushort* __restrict__ feat, const float* __restrict__ el,
    const float* __restrict__ er, const float* __restrict__ bias,
    ushort* __restrict__ hhi, ushort* __restrict__ hlo, int N) {
  int lane = threadIdx.x & 63;
  int v = blockIdx.x * 4 + (threadIdx.x >> 6);
  if (v >= N) return;
  float4 er4 = *(const float4*)(er + (size_t)v * 4);
  int r0 = rowptr[v], r1 = rowptr[v + 1];
  // pass 1: per-head max (edges strided over lanes; el row = float4)
  float m0 = -1e30f, m1 = -1e30f, m2 = -1e30f, m3 = -1e30f;
  for (int i = r0 + lane; i < r1; i += 64) {
    int s = csr_src[i];
    float4 e4 = *(const float4*)(el + (size_t)s * 4);
    m0 = fmaxf(m0, lrelu(e4.x + er4.x));
    m1 = fmaxf(m1, lrelu(e4.y + er4.y));
    m2 = fmaxf(m2, lrelu(e4.z + er4.z));
    m3 = fmaxf(m3, lrelu(e4.w + er4.w));
  }
#pragma unroll
  for (int off = 32; off > 0; off >>= 1) {
    m0 = fmaxf(m0, __shfl_xor(m0, off));
    m1 = fmaxf(m1, __shfl_xor(m1, off));
    m2 = fmaxf(m2, __shfl_xor(m2, off));
    m3 = fmaxf(m3, __shfl_xor(m3, off));
  }
  // chunked pass 2: lanes 4j..4j+3 compute exp for (edge i0+j, head 0..3),
  // then 16-deep FMA loop with shuffle broadcast (independent gathers).
  int hh = lane & 3;
  float mh = (hh == 0) ? m0 : (hh == 1) ? m1 : (hh == 2) ? m2 : m3;
  float eh = (hh == 0) ? er4.x : (hh == 1) ? er4.y : (hh == 2) ? er4.z : er4.w;
  int hf = lane >> 4;  // head owning features 2*lane, 2*lane+1
  const uint* fb = (const uint*)feat;
  float a0 = 0.f, a1 = 0.f, den = 0.f;
  for (int i0 = r0; i0 < r1; i0 += 16) {
    int i = i0 + (lane >> 2);
    int sv = 0;
    float xv = 0.f;
    if (i < r1) {
      sv = csr_src[i];
      float e = lrelu(el[(size_t)sv * 4 + hh] + eh);
      xv = __expf(e - mh);
    }
    int cnt = r1 - i0;
    if (cnt > 16) cnt = 16;
    for (int j = 0; j < cnt; ++j) {
      int s = __shfl(sv, j * 4);
      float x = __shfl(xv, j * 4 + hf);
      uint u = fb[(size_t)s * 64 + lane];
      den += x;
      a0 += x * lo2f(u);
      a1 += x * hi2f(u);
    }
  }
  float o0 = (den > 0.f) ? a0 / den : 0.f;
  float o1 = (den > 0.f) ? a1 / den : 0.f;
  o0 = fmaxf(o0 + bias[2 * lane], 0.f);
  o1 = fmaxf(o1 + bias[2 * lane + 1], 0.f);
  ushort h0 = f2bu(o0), h1 = f2bu(o1);
  ushort l0 = f2bu(o0 - bu2f(h0)), l1 = f2bu(o1 - bu2f(h1));
  ((uint*)hhi)[(size_t)v * 64 + lane] = (uint)h0 | ((uint)h1 << 16);
  ((uint*)hlo)[(size_t)v * 64 + lane] = (uint)l0 | ((uint)l1 << 16);
}

// ---------------- fused layer 3 aggregation + bias + head-mean + log_softmax ----------------
__global__ __launch_bounds__(256) void agg3_kernel(
    const int* __restrict__ rowptr, const int* __restrict__ csr_src,
    const ushort* __restrict__ feat, const float* __restrict__ el,
    const float* __restrict__ er, const float* __restrict__ bias,
    float* __restrict__ out, int N) {
  __shared__ float svm[4][188];
  int lane = threadIdx.x & 63;
  int w = threadIdx.x >> 6;
  int v = blockIdx.x * 4 + w;
  bool valid = (v < N);
  float4 er4 = {0.f, 0.f, 0.f, 0.f};
  int r0 = 0, r1 = 0;
  if (valid) {
    er4 = *(const float4*)(er + (size_t)v * 4);
    r0 = rowptr[v];
    r1 = rowptr[v + 1];
  }
  float m0 = -1e30f, m1 = -1e30f, m2 = -1e30f, m3 = -1e30f;
  for (int i = r0 + lane; i < r1; i += 64) {
    int s = csr_src[i];
    float4 e4 = *(const float4*)(el + (size_t)s * 4);
    m0 = fmaxf(m0, lrelu(e4.x + er4.x));
    m1 = fmaxf(m1, lrelu(e4.y + er4.y));
    m2 = fmaxf(m2, lrelu(e4.z + er4.z));
    m3 = fmaxf(m3, lrelu(e4.w + er4.w));
  }
#pragma unroll
  for (int off = 32; off > 0; off >>= 1) {
    m0 = fmaxf(m0, __shfl_xor(m0, off));
    m1 = fmaxf(m1, __shfl_xor(m1, off));
    m2 = fmaxf(m2, __shfl_xor(m2, off));
    m3 = fmaxf(m3, __shfl_xor(m3, off));
  }
  int hh = lane & 3;
  float mh = (hh == 0) ? m0 : (hh == 1) ? m1 : (hh == 2) ? m2 : m3;
  float eh = (hh == 0) ? er4.x : (hh == 1) ? er4.y : (hh == 2) ? er4.z : er4.w;
  // lane owns features 2l,2l+1 and (lanes<30) 128+2l,129+2l
  int fa = 2 * lane, fbi = 2 * lane + 1;
  int fc = 128 + 2 * lane, fd = 129 + 2 * lane;
  bool hasC = (fd < 188);
  int ha = fa / 47, hb = fbi / 47;
  int hc = hasC ? fc / 47 : 3, hd = hasC ? fd / 47 : 3;
  const uint* fpb = (const uint*)feat;  // feat row: 94 uints
  float aa = 0.f, ab = 0.f, ac = 0.f, ad = 0.f;
  float da = 0.f, db = 0.f, dc = 0.f, dd = 0.f;
  for (int i0 = r0; i0 < r1; i0 += 16) {
    int i = i0 + (lane >> 2);
    int sv = 0;
    float xv = 0.f;
    if (i < r1) {
      sv = csr_src[i];
      float e = lrelu(el[(size_t)sv * 4 + hh] + eh);
      xv = __expf(e - mh);
    }
    int cnt = r1 - i0;
    if (cnt > 16) cnt = 16;
    for (int j = 0; j < cnt; ++j) {
      int s = __shfl(sv, j * 4);
      float xa = __shfl(xv, j * 4 + ha);
      float xb = __shfl(xv, j * 4 + hb);
      uint u0 = fpb[(size_t)s * 94 + lane];
      da += xa; db += xb;
      aa += xa * lo2f(u0);
      ab += xb * hi2f(u0);
      if (hasC) {
        float xc = __shfl(xv, j * 4 + hc);
        float xd = __shfl(xv, j * 4 + hd);
        uint u1 = fpb[(size_t)s * 94 + 64 + lane];
        dc += xc; dd += xd;
        ac += xc * lo2f(u1);
        ad += xd * hi2f(u1);
      }
    }
  }
  float oa = ((da > 0.f) ? aa / da : 0.f) + bias[fa];
  float ob = ((db > 0.f) ? ab / db : 0.f) + bias[fbi];
  if (valid) {
    svm[w][fa] = oa;
    svm[w][fbi] = ob;
    if (hasC) {
      float oc = ((dc > 0.f) ? ac / dc : 0.f) + bias[fc];
      float od = ((dd > 0.f) ? ad / dd : 0.f) + bias[fd];
      svm[w][fc] = oc;
      svm[w][fd] = od;
    }
  }
  __syncthreads();
  float val = -1e30f;
  if (valid && lane < 47)
    val = 0.25f * (svm[w][lane] + svm[w][47 + lane] + svm[w][94 + lane] + svm[w][141 + lane]);
  float mx = val;
#pragma unroll
  for (int off = 32; off > 0; off >>= 1) mx = fmaxf(mx, __shfl_xor(mx, off));
  float ex = (lane < 47) ? __expf(val - mx) : 0.f;
  float sum = ex;
#pragma unroll
  for (int off = 32; off > 0; off >>= 1) sum += __shfl_xor(sum, off);
  float res = val - mx - logf(sum);
  if (valid && lane < 47) out[(size_t)v * 47 + lane] = res;
}

// ---------------- host orchestration ----------------
extern "C" void kernel_launch(void* const* d_in, const int* in_sizes, int n_in,
                              void* d_out, int out_size, void* d_ws, size_t ws_size,
                              hipStream_t stream) {
  const int N = 100000, E = 1600000, IN = 256;
  const int F = 128;   // H*D
  const int F3 = 188;  // H*C

  const float* x = (const float*)d_in[0];
  const int* src = (const int*)d_in[1];
  const int* dst = (const int*)d_in[2];
  const float* W1 = (const float*)d_in[3];
  const float* al1 = (const float*)d_in[4];
  const float* ar1 = (const float*)d_in[5];
  const float* b1 = (const float*)d_in[6];
  const float* W2 = (const float*)d_in[7];
  const float* al2 = (const float*)d_in[8];
  const float* ar2 = (const float*)d_in[9];
  const float* b2 = (const float*)d_in[10];
  const float* W3 = (const float*)d_in[11];
  const float* al3 = (const float*)d_in[12];
  const float* ar3 = (const float*)d_in[13];
  const float* b3 = (const float*)d_in[14];

  char* p = (char*)d_ws;
  auto alloc = [&](size_t bytes) -> char* {
    char* r = p;
    p += (bytes + 255) & ~(size_t)255;
    return r;
  };
  ushort* xhi = (ushort*)alloc((size_t)N * IN * sizeof(ushort));
  ushort* xlo = (ushort*)alloc((size_t)N * IN * sizeof(ushort));
  ushort* feat = (ushort*)alloc((size_t)N * F3 * sizeof(ushort));
  ushort* Wt1h = (ushort*)alloc((size_t)F * IN * sizeof(ushort));
  ushort* Wt1l = (ushort*)alloc((size_t)F * IN * sizeof(ushort));
  ushort* Wt2h = (ushort*)alloc((size_t)F * F * sizeof(ushort));
  ushort* Wt2l = (ushort*)alloc((size_t)F * F * sizeof(ushort));
  ushort* Wt3h = (ushort*)alloc((size_t)F3 * F * sizeof(ushort));
  ushort* Wt3l = (ushort*)alloc((size_t)F3 * F * sizeof(ushort));
  float* el = (float*)alloc((size_t)N * 4 * sizeof(float));
  float* er = (float*)alloc((size_t)N * 4 * sizeof(float));
  int* deg = (int*)alloc((size_t)N * sizeof(int));
  int* part = (int*)alloc((size_t)N * sizeof(int));
  int* bsums = (int*)alloc(256 * sizeof(int));
  int* rowptr = (int*)alloc((size_t)(N + 1) * sizeof(int));
  int* cursor = (int*)alloc((size_t)N * sizeof(int));
  int* csr_src = (int*)alloc((size_t)E * sizeof(int));

  // h (layers 2/3 input) aliases the x split buffers — x is consumed by the
  // layer-1 GEMM before agg128 overwrites these (single-stream ordering).
  ushort* hhi = xhi;
  ushort* hlo = xlo;

  // ---- CSR build ----
  zero_int_kernel<<<(N + 255) / 256, 256, 0, stream>>>(deg, N);
  hist_kernel<<<(E + 255) / 256, 256, 0, stream>>>(dst, deg, E);
  int nb = (N + 1023) / 1024;
  scan1_kernel<<<nb, 256, 0, stream>>>(deg, part, bsums, N);
  scan2_kernel<<<1, 256, 0, stream>>>(bsums, nb);
  scan3_kernel<<<(N + 255) / 256, 256, 0, stream>>>(part, bsums, rowptr, cursor, N, E);
  scatter_kernel<<<(E + 255) / 256, 256, 0, stream>>>(src, dst, cursor, csr_src, E);

  // ---- splits ----
  splitx_kernel<<<(N * IN / 4 + 255) / 256, 256, 0, stream>>>(x, xhi, xlo, N * IN);
  splitW_kernel<<<(IN * F + 255) / 256, 256, 0, stream>>>(W1, Wt1h, Wt1l, IN, F);
  splitW_kernel<<<(F * F + 255) / 256, 256, 0, stream>>>(W2, Wt2h, Wt2l, F, F);
  splitW_kernel<<<(F * F3 + 255) / 256, 256, 0, stream>>>(W3, Wt3h, Wt3l, F, F3);

  int rowBlocks = (N + GBM - 1) / GBM;  // 782
  int nodeBlocks = (N + 3) / 4;

  // ---- layer 1: IN=256 -> 128 ----
  gemm_split_kernel<<<dim3(F / GBN, rowBlocks), 256, 0, stream>>>(
      xhi, xlo, Wt1h, Wt1l, feat, N, IN, F);
  elr_kernel<<<(N * 4 + 255) / 256, 256, 0, stream>>>(feat, al1, ar1, el, er, N, 32, F);
  agg128_kernel<<<nodeBlocks, 256, 0, stream>>>(rowptr, csr_src, feat, el, er, b1, hhi, hlo, N);

  // ---- layer 2: 128 -> 128 ----
  gemm_split_kernel<<<dim3(F / GBN, rowBlocks), 256, 0, stream>>>(
      hhi, hlo, Wt2h, Wt2l, feat, N, F, F);
  elr_kernel<<<(N * 4 + 255) / 256, 256, 0, stream>>>(feat, al2, ar2, el, er, N, 32, F);
  agg128_kernel<<<nodeBlocks, 256, 0, stream>>>(rowptr, csr_src, feat, el, er, b2, hhi, hlo, N);

  // ---- layer 3: 128 -> 188, fused epilogue ----
  gemm_split_kernel<<<dim3((F3 + GBN - 1) / GBN, rowBlocks), 256, 0, stream>>>(
      hhi, hlo, Wt3h, Wt3l, feat, N, F, F3);
  elr_kernel<<<(N * 4 + 255) / 256, 256, 0, stream>>>(feat, al3, ar3, el, er, N, 47, F3);
  agg3_kernel<<<nodeBlocks, 256, 0, stream>>>(rowptr, csr_src, feat, el, er, b3,
                                              (float*)d_out, N);
}

// Round 7
// 996.015 us; speedup vs baseline: 1.5696x; 1.1165x over previous
//
#include <hip/hip_runtime.h>
#include <hip/hip_bf16.h>

typedef unsigned short ushort;
typedef unsigned int uint;
typedef __attribute__((ext_vector_type(8))) short short8;
typedef __attribute__((ext_vector_type(4))) float floatx4;

#define NEG_SLOPE 0.2f

__device__ __forceinline__ float bu2f(ushort u) {
  uint t = ((uint)u) << 16;
  return __uint_as_float(t);
}
__device__ __forceinline__ ushort f2bu(float f) {
  __hip_bfloat16 h = __float2bfloat16(f);
  return *(ushort*)&h;
}
__device__ __forceinline__ float lo2f(uint u) { return __uint_as_float(u << 16); }
__device__ __forceinline__ float hi2f(uint u) { return __uint_as_float(u & 0xffff0000u); }
__device__ __forceinline__ float lrelu(float e) { return (e > 0.f) ? e : NEG_SLOPE * e; }

// ---------------- CSR build ----------------
__global__ void zero_int_kernel(int* __restrict__ p, int n) {
  int i = blockIdx.x * blockDim.x + threadIdx.x;
  if (i < n) p[i] = 0;
}

__global__ void hist_kernel(const int* __restrict__ dst, int* __restrict__ deg, int E) {
  int e = blockIdx.x * blockDim.x + threadIdx.x;
  if (e < E) atomicAdd(&deg[dst[e]], 1);
}

__global__ void scan1_kernel(const int* __restrict__ deg, int* __restrict__ part,
                             int* __restrict__ bsums, int n) {
  __shared__ int sdata[256];
  int t = threadIdx.x;
  int base = blockIdx.x * 1024;
  int v[4]; int s = 0;
#pragma unroll
  for (int j = 0; j < 4; ++j) {
    int idx = base + t * 4 + j;
    v[j] = (idx < n) ? deg[idx] : 0;
    s += v[j];
  }
  sdata[t] = s;
  __syncthreads();
  for (int off = 1; off < 256; off <<= 1) {
    int x = 0;
    if (t >= off) x = sdata[t - off];
    __syncthreads();
    if (t >= off) sdata[t] += x;
    __syncthreads();
  }
  if (t == 255) bsums[blockIdx.x] = sdata[255];
  int run = (t > 0) ? sdata[t - 1] : 0;
#pragma unroll
  for (int j = 0; j < 4; ++j) {
    int idx = base + t * 4 + j;
    if (idx < n) part[idx] = run;
    run += v[j];
  }
}

__global__ void scan2_kernel(int* __restrict__ bsums, int nb) {
  __shared__ int sdata[256];
  int t = threadIdx.x;
  sdata[t] = (t < nb) ? bsums[t] : 0;
  __syncthreads();
  for (int off = 1; off < 256; off <<= 1) {
    int x = 0;
    if (t >= off) x = sdata[t - off];
    __syncthreads();
    if (t >= off) sdata[t] += x;
    __syncthreads();
  }
  if (t < nb) bsums[t] = (t > 0) ? sdata[t - 1] : 0;
}

__global__ void scan3_kernel(const int* __restrict__ part, const int* __restrict__ bsums,
                             int* __restrict__ rowptr, int* __restrict__ cursor,
                             int n, int Etot) {
  int i = blockIdx.x * blockDim.x + threadIdx.x;
  if (i < n) {
    int v = part[i] + bsums[i >> 10];
    rowptr[i] = v;
    cursor[i] = v;
  }
  if (i == 0) rowptr[n] = Etot;
}

__global__ void scatter_kernel(const int* __restrict__ src, const int* __restrict__ dst,
                               int* __restrict__ cursor, int* __restrict__ csr_src, int E) {
  int e = blockIdx.x * blockDim.x + threadIdx.x;
  if (e < E) {
    int pos = atomicAdd(&cursor[dst[e]], 1);
    csr_src[pos] = src[e];
  }
}

// ---------------- splits ----------------
__global__ void splitx_kernel(const float* __restrict__ x, ushort* __restrict__ xhi,
                              ushort* __restrict__ xlo, int n) {
  int base = (blockIdx.x * blockDim.x + threadIdx.x) * 4;
  if (base >= n) return;
  float4 a = *(const float4*)(x + base);
  float v[4] = {a.x, a.y, a.z, a.w};
  ushort hi[4], lo[4];
#pragma unroll
  for (int j = 0; j < 4; ++j) {
    hi[j] = f2bu(v[j]);
    lo[j] = f2bu(v[j] - bu2f(hi[j]));
  }
  uint2 ho, loo;
  ho.x = (uint)hi[0] | ((uint)hi[1] << 16);
  ho.y = (uint)hi[2] | ((uint)hi[3] << 16);
  loo.x = (uint)lo[0] | ((uint)lo[1] << 16);
  loo.y = (uint)lo[2] | ((uint)lo[3] << 16);
  *(uint2*)(xhi + base) = ho;
  *(uint2*)(xlo + base) = loo;
}

__global__ void splitW_kernel(const float* __restrict__ W, ushort* __restrict__ WtH,
                              ushort* __restrict__ WtL, int K, int Nc) {
  int idx = blockIdx.x * blockDim.x + threadIdx.x;
  if (idx >= K * Nc) return;
  int n = idx / K, k = idx - n * K;
  float w = W[(size_t)k * Nc + n];
  ushort hi = f2bu(w);
  WtH[idx] = hi;
  WtL[idx] = f2bu(w - bu2f(hi));
}

// ---------------- split-bf16 MFMA GEMM ----------------
#define GBM 128
#define GBN 64
#define GBK 32
#define SA 40

__global__ __launch_bounds__(256) void gemm_split_kernel(
    const ushort* __restrict__ Ah, const ushort* __restrict__ Al,
    const ushort* __restrict__ Bh, const ushort* __restrict__ Bl,
    ushort* __restrict__ C, int M, int K, int Nc) {
  __shared__ ushort AsH[GBM * SA];
  __shared__ ushort AsL[GBM * SA];
  __shared__ ushort BsH[GBN * SA];
  __shared__ ushort BsL[GBN * SA];
  int tid = threadIdx.x;
  int lane = tid & 63;
  int wave = tid >> 6;
  int wm = wave & 1, wn = wave >> 1;
  int rowBase = blockIdx.y * GBM;
  int colBase = blockIdx.x * GBN;
  int q = lane >> 4;
  int ln = lane & 15;

  floatx4 acc[4][2] = {};

  for (int k0 = 0; k0 < K; k0 += GBK) {
#pragma unroll
    for (int it = 0; it < 2; ++it) {
      int i = tid + it * 256;
      int r = i >> 2, seg = i & 3;
      int grow = rowBase + r;
      uint4 vh = {0u, 0u, 0u, 0u}, vl = {0u, 0u, 0u, 0u};
      if (grow < M) {
        size_t off = (size_t)grow * K + k0 + seg * 8;
        vh = *(const uint4*)(Ah + off);
        vl = *(const uint4*)(Al + off);
      }
      *(uint4*)&AsH[r * SA + seg * 8] = vh;
      *(uint4*)&AsL[r * SA + seg * 8] = vl;
    }
    {
      int n = tid >> 2, seg = tid & 3;
      int gcol = colBase + n;
      uint4 vh = {0u, 0u, 0u, 0u}, vl = {0u, 0u, 0u, 0u};
      if (gcol < Nc) {
        size_t off = (size_t)gcol * K + k0 + seg * 8;
        vh = *(const uint4*)(Bh + off);
        vl = *(const uint4*)(Bl + off);
      }
      *(uint4*)&BsH[n * SA + seg * 8] = vh;
      *(uint4*)&BsL[n * SA + seg * 8] = vl;
    }
    __syncthreads();
    short8 afH[4], afL[4], bfH[2], bfL[2];
#pragma unroll
    for (int mt = 0; mt < 4; ++mt) {
      int r = (wm * 64 + mt * 16 + ln) * SA + q * 8;
      afH[mt] = *(const short8*)&AsH[r];
      afL[mt] = *(const short8*)&AsL[r];
    }
#pragma unroll
    for (int nt = 0; nt < 2; ++nt) {
      int r = (wn * 32 + nt * 16 + ln) * SA + q * 8;
      bfH[nt] = *(const short8*)&BsH[r];
      bfL[nt] = *(const short8*)&BsL[r];
    }
#pragma unroll
    for (int mt = 0; mt < 4; ++mt)
#pragma unroll
      for (int nt = 0; nt < 2; ++nt) {
        acc[mt][nt] = __builtin_amdgcn_mfma_f32_16x16x32_bf16(afH[mt], bfH[nt], acc[mt][nt], 0, 0, 0);
        acc[mt][nt] = __builtin_amdgcn_mfma_f32_16x16x32_bf16(afH[mt], bfL[nt], acc[mt][nt], 0, 0, 0);
        acc[mt][nt] = __builtin_amdgcn_mfma_f32_16x16x32_bf16(afL[mt], bfH[nt], acc[mt][nt], 0, 0, 0);
      }
    __syncthreads();
  }
#pragma unroll
  for (int mt = 0; mt < 4; ++mt) {
#pragma unroll
    for (int nt = 0; nt < 2; ++nt) {
      int col = colBase + wn * 32 + nt * 16 + ln;
      if (col < Nc) {
#pragma unroll
        for (int r = 0; r < 4; ++r) {
          int row = rowBase + wm * 64 + mt * 16 + q * 4 + r;
          if (row < M) C[(size_t)row * Nc + col] = f2bu(acc[mt][nt][r]);
        }
      }
    }
  }
}

// ---------------- el/er layer 1/2 (Dh=32, F=128): vectorized uint4 loads ----------------
__global__ void elr128_kernel(const ushort* __restrict__ feat, const float* __restrict__ al,
                              const float* __restrict__ ar, float* __restrict__ el,
                              float* __restrict__ er, int N) {
  int g = blockIdx.x * blockDim.x + threadIdx.x;
  if (g >= N * 4) return;
  int n = g >> 2, h = g & 3;
  const uint4* fp = (const uint4*)(feat + (size_t)n * 128 + h * 32);
  const float* alp = al + h * 32;
  const float* arp = ar + h * 32;
  float sl = 0.f, sr = 0.f;
#pragma unroll
  for (int b = 0; b < 4; ++b) {
    uint4 u = fp[b];
    uint w[4] = {u.x, u.y, u.z, u.w};
#pragma unroll
    for (int j = 0; j < 4; ++j) {
      int d = b * 8 + j * 2;
      float f0 = lo2f(w[j]), f1 = hi2f(w[j]);
      sl += f0 * alp[d] + f1 * alp[d + 1];
      sr += f0 * arp[d] + f1 * arp[d + 1];
    }
  }
  el[g] = sl;
  er[g] = sr;
}

// ---------------- el/er layer 3 (Dh=47, F=188): scalar ----------------
__global__ void elr3_kernel(const ushort* __restrict__ feat, const float* __restrict__ al,
                            const float* __restrict__ ar, float* __restrict__ el,
                            float* __restrict__ er, int N) {
  int g = blockIdx.x * blockDim.x + threadIdx.x;
  if (g >= N * 4) return;
  int n = g >> 2, h = g & 3;
  const ushort* fp = feat + (size_t)n * 188 + h * 47;
  float sl = 0.f, sr = 0.f;
  for (int d = 0; d < 47; ++d) {
    float f = bu2f(fp[d]);
    sl += f * al[h * 47 + d];
    sr += f * ar[h * 47 + d];
  }
  el[g] = sl;
  er[g] = sr;
}

// ---------------- fused layer 1/2 aggregation (no max pass), wave/node ----------------
__global__ __launch_bounds__(256) void agg128_kernel(
    const int* __restrict__ rowptr, const int* __restrict__ csr_src,
    const ushort* __restrict__ feat, const float* __restrict__ el,
    const float* __restrict__ er, const float* __restrict__ bias,
    ushort* __restrict__ hhi, ushort* __restrict__ hlo, int N) {
  int lane = threadIdx.x & 63;
  int v = blockIdx.x * 4 + (threadIdx.x >> 6);
  if (v >= N) return;
  float4 er4 = *(const float4*)(er + (size_t)v * 4);
  int r0 = rowptr[v], r1 = rowptr[v + 1];
  // chunked: lanes 4j..4j+3 compute exp for (edge i0+j, head 0..3),
  // then 16-deep FMA loop with shuffle broadcast (independent gathers).
  int hh = lane & 3;
  float eh = (hh == 0) ? er4.x : (hh == 1) ? er4.y : (hh == 2) ? er4.z : er4.w;
  int hf = lane >> 4;  // head owning features 2*lane, 2*lane+1
  const uint* fb = (const uint*)feat;
  float a0 = 0.f, a1 = 0.f, den = 0.f;
  for (int i0 = r0; i0 < r1; i0 += 16) {
    int i = i0 + (lane >> 2);
    int sv = 0;
    float xv = 0.f;
    if (i < r1) {
      sv = csr_src[i];
      xv = __expf(lrelu(el[(size_t)sv * 4 + hh] + eh));
    }
    int cnt = r1 - i0;
    if (cnt > 16) cnt = 16;
    for (int j = 0; j < cnt; ++j) {
      int s = __shfl(sv, j * 4);
      float x = __shfl(xv, j * 4 + hf);
      uint u = fb[(size_t)s * 64 + lane];
      den += x;
      a0 += x * lo2f(u);
      a1 += x * hi2f(u);
    }
  }
  float o0 = (den > 0.f) ? a0 / den : 0.f;
  float o1 = (den > 0.f) ? a1 / den : 0.f;
  o0 = fmaxf(o0 + bias[2 * lane], 0.f);
  o1 = fmaxf(o1 + bias[2 * lane + 1], 0.f);
  ushort h0 = f2bu(o0), h1 = f2bu(o1);
  ushort l0 = f2bu(o0 - bu2f(h0)), l1 = f2bu(o1 - bu2f(h1));
  ((uint*)hhi)[(size_t)v * 64 + lane] = (uint)h0 | ((uint)h1 << 16);
  ((uint*)hlo)[(size_t)v * 64 + lane] = (uint)l0 | ((uint)l1 << 16);
}

// ---------------- fused layer 3 aggregation + bias + head-mean + log_softmax ----------------
__global__ __launch_bounds__(256) void agg3_kernel(
    const int* __restrict__ rowptr, const int* __restrict__ csr_src,
    const ushort* __restrict__ feat, const float* __restrict__ el,
    const float* __restrict__ er, const float* __restrict__ bias,
    float* __restrict__ out, int N) {
  __shared__ float svm[4][188];
  int lane = threadIdx.x & 63;
  int w = threadIdx.x >> 6;
  int v = blockIdx.x * 4 + w;
  bool valid = (v < N);
  float4 er4 = {0.f, 0.f, 0.f, 0.f};
  int r0 = 0, r1 = 0;
  if (valid) {
    er4 = *(const float4*)(er + (size_t)v * 4);
    r0 = rowptr[v];
    r1 = rowptr[v + 1];
  }
  int hh = lane & 3;
  float eh = (hh == 0) ? er4.x : (hh == 1) ? er4.y : (hh == 2) ? er4.z : er4.w;
  // lane owns features 2l,2l+1 and (lanes<30) 128+2l,129+2l
  int fa = 2 * lane, fbi = 2 * lane + 1;
  int fc = 128 + 2 * lane, fd = 129 + 2 * lane;
  bool hasC = (fd < 188);
  int ha = fa / 47, hb = fbi / 47;
  int hc = hasC ? fc / 47 : 3, hd = hasC ? fd / 47 : 3;
  const uint* fpb = (const uint*)feat;  // feat row: 94 uints
  float aa = 0.f, ab = 0.f, ac = 0.f, ad = 0.f;
  float da = 0.f, db = 0.f, dc = 0.f, dd = 0.f;
  for (int i0 = r0; i0 < r1; i0 += 16) {
    int i = i0 + (lane >> 2);
    int sv = 0;
    float xv = 0.f;
    if (i < r1) {
      sv = csr_src[i];
      xv = __expf(lrelu(el[(size_t)sv * 4 + hh] + eh));
    }
    int cnt = r1 - i0;
    if (cnt > 16) cnt = 16;
    for (int j = 0; j < cnt; ++j) {
      int s = __shfl(sv, j * 4);
      float xa = __shfl(xv, j * 4 + ha);
      float xb = __shfl(xv, j * 4 + hb);
      uint u0 = fpb[(size_t)s * 94 + lane];
      da += xa; db += xb;
      aa += xa * lo2f(u0);
      ab += xb * hi2f(u0);
      if (hasC) {
        float xc = __shfl(xv, j * 4 + hc);
        float xd = __shfl(xv, j * 4 + hd);
        uint u1 = fpb[(size_t)s * 94 + 64 + lane];
        dc += xc; dd += xd;
        ac += xc * lo2f(u1);
        ad += xd * hi2f(u1);
      }
    }
  }
  float oa = ((da > 0.f) ? aa / da : 0.f) + bias[fa];
  float ob = ((db > 0.f) ? ab / db : 0.f) + bias[fbi];
  if (valid) {
    svm[w][fa] = oa;
    svm[w][fbi] = ob;
    if (hasC) {
      float oc = ((dc > 0.f) ? ac / dc : 0.f) + bias[fc];
      float od = ((dd > 0.f) ? ad / dd : 0.f) + bias[fd];
      svm[w][fc] = oc;
      svm[w][fd] = od;
    }
  }
  __syncthreads();
  float val = -1e30f;
  if (valid && lane < 47)
    val = 0.25f * (svm[w][lane] + svm[w][47 + lane] + svm[w][94 + lane] + svm[w][141 + lane]);
  float mx = val;
#pragma unroll
  for (int off = 32; off > 0; off >>= 1) mx = fmaxf(mx, __shfl_xor(mx, off));
  float ex = (lane < 47) ? __expf(val - mx) : 0.f;
  float sum = ex;
#pragma unroll
  for (int off = 32; off > 0; off >>= 1) sum += __shfl_xor(sum, off);
  float res = val - mx - logf(sum);
  if (valid && lane < 47) out[(size_t)v * 47 + lane] = res;
}

// ---------------- host orchestration ----------------
extern "C" void kernel_launch(void* const* d_in, const int* in_sizes, int n_in,
                              void* d_out, int out_size, void* d_ws, size_t ws_size,
                              hipStream_t stream) {
  const int N = 100000, E = 1600000, IN = 256;
  const int F = 128;   // H*D
  const int F3 = 188;  // H*C

  const float* x = (const float*)d_in[0];
  const int* src = (const int*)d_in[1];
  const int* dst = (const int*)d_in[2];
  const float* W1 = (const float*)d_in[3];
  const float* al1 = (const float*)d_in[4];
  const float* ar1 = (const float*)d_in[5];
  const float* b1 = (const float*)d_in[6];
  const float* W2 = (const float*)d_in[7];
  const float* al2 = (const float*)d_in[8];
  const float* ar2 = (const float*)d_in[9];
  const float* b2 = (const float*)d_in[10];
  const float* W3 = (const float*)d_in[11];
  const float* al3 = (const float*)d_in[12];
  const float* ar3 = (const float*)d_in[13];
  const float* b3 = (const float*)d_in[14];

  char* p = (char*)d_ws;
  auto alloc = [&](size_t bytes) -> char* {
    char* r = p;
    p += (bytes + 255) & ~(size_t)255;
    return r;
  };
  ushort* xhi = (ushort*)alloc((size_t)N * IN * sizeof(ushort));
  ushort* xlo = (ushort*)alloc((size_t)N * IN * sizeof(ushort));
  ushort* feat = (ushort*)alloc((size_t)N * F3 * sizeof(ushort));
  ushort* Wt1h = (ushort*)alloc((size_t)F * IN * sizeof(ushort));
  ushort* Wt1l = (ushort*)alloc((size_t)F * IN * sizeof(ushort));
  ushort* Wt2h = (ushort*)alloc((size_t)F * F * sizeof(ushort));
  ushort* Wt2l = (ushort*)alloc((size_t)F * F * sizeof(ushort));
  ushort* Wt3h = (ushort*)alloc((size_t)F3 * F * sizeof(ushort));
  ushort* Wt3l = (ushort*)alloc((size_t)F3 * F * sizeof(ushort));
  float* el = (float*)alloc((size_t)N * 4 * sizeof(float));
  float* er = (float*)alloc((size_t)N * 4 * sizeof(float));
  int* deg = (int*)alloc((size_t)N * sizeof(int));
  int* part = (int*)alloc((size_t)N * sizeof(int));
  int* bsums = (int*)alloc(256 * sizeof(int));
  int* rowptr = (int*)alloc((size_t)(N + 1) * sizeof(int));
  int* cursor = (int*)alloc((size_t)N * sizeof(int));
  int* csr_src = (int*)alloc((size_t)E * sizeof(int));

  // h (layers 2/3 input) aliases the x split buffers — x is consumed by the
  // layer-1 GEMM before agg128 overwrites these (single-stream ordering).
  ushort* hhi = xhi;
  ushort* hlo = xlo;

  // ---- CSR build ----
  zero_int_kernel<<<(N + 255) / 256, 256, 0, stream>>>(deg, N);
  hist_kernel<<<(E + 255) / 256, 256, 0, stream>>>(dst, deg, E);
  int nb = (N + 1023) / 1024;
  scan1_kernel<<<nb, 256, 0, stream>>>(deg, part, bsums, N);
  scan2_kernel<<<1, 256, 0, stream>>>(bsums, nb);
  scan3_kernel<<<(N + 255) / 256, 256, 0, stream>>>(part, bsums, rowptr, cursor, N, E);
  scatter_kernel<<<(E + 255) / 256, 256, 0, stream>>>(src, dst, cursor, csr_src, E);

  // ---- splits ----
  splitx_kernel<<<(N * IN / 4 + 255) / 256, 256, 0, stream>>>(x, xhi, xlo, N * IN);
  splitW_kernel<<<(IN * F + 255) / 256, 256, 0, stream>>>(W1, Wt1h, Wt1l, IN, F);
  splitW_kernel<<<(F * F + 255) / 256, 256, 0, stream>>>(W2, Wt2h, Wt2l, F, F);
  splitW_kernel<<<(F * F3 + 255) / 256, 256, 0, stream>>>(W3, Wt3h, Wt3l, F, F3);

  int rowBlocks = (N + GBM - 1) / GBM;  // 782
  int nodeBlocks = (N + 3) / 4;

  // ---- layer 1: IN=256 -> 128 ----
  gemm_split_kernel<<<dim3(F / GBN, rowBlocks), 256, 0, stream>>>(
      xhi, xlo, Wt1h, Wt1l, feat, N, IN, F);
  elr128_kernel<<<(N * 4 + 255) / 256, 256, 0, stream>>>(feat, al1, ar1, el, er, N);
  agg128_kernel<<<nodeBlocks, 256, 0, stream>>>(rowptr, csr_src, feat, el, er, b1, hhi, hlo, N);

  // ---- layer 2: 128 -> 128 ----
  gemm_split_kernel<<<dim3(F / GBN, rowBlocks), 256, 0, stream>>>(
      hhi, hlo, Wt2h, Wt2l, feat, N, F, F);
  elr128_kernel<<<(N * 4 + 255) / 256, 256, 0, stream>>>(feat, al2, ar2, el, er, N);
  agg128_kernel<<<nodeBlocks, 256, 0, stream>>>(rowptr, csr_src, feat, el, er, b2, hhi, hlo, N);

  // ---- layer 3: 128 -> 188, fused epilogue ----
  gemm_split_kernel<<<dim3((F3 + GBN - 1) / GBN, rowBlocks), 256, 0, stream>>>(
      hhi, hlo, Wt3h, Wt3l, feat, N, F, F3);
  elr3_kernel<<<(N * 4 + 255) / 256, 256, 0, stream>>>(feat, al3, ar3, el, er, N);
  agg3_kernel<<<nodeBlocks, 256, 0, stream>>>(rowptr, csr_src, feat, el, er, b3,
                                              (float*)d_out, N);
}